// Round 3
// baseline (105727.332 us; speedup 1.0000x reference)
//
#include <hip/hip_runtime.h>
#include <hip/hip_cooperative_groups.h>
#include <cstdint>
#include <cstddef>

namespace cg = cooperative_groups;

// ---------------------------------------------------------------------------
// Tacotron2 decoder, MI355X. Round 7: revert to round-5 structure (15.5 ms,
// verified) and move the 250-step loop into ONE persistent cooperative kernel
// (grid 512x256, 2 blocks/CU co-resident). Same six phase bodies, same block
// decompositions, same fp reduction orders -> bit-identical output target.
// grid.sync() replaces 1500 kernel boundaries. Fallback: if cooperative
// launch fails (validation/capture), issue the exact round-5 kernel sequence.
// ---------------------------------------------------------------------------

static constexpr int NSTEP = 250;

// workspace offsets (floats). total = 19,322,880 floats (~77.3 MB)
static constexpr size_t OFF_ENCPROJ = 0;               // 819200
static constexpr size_t OFF_CWT     = 819200;          // 4096
static constexpr size_t OFF_KEYS    = 823296;          // 2048 (250*8 uints)
static constexpr size_t OFF_PRE2    = 825344;          // 2048000
static constexpr size_t OFF_G       = 2873344;         // 4096000
static constexpr size_t OFF_S2      = 6969344;         // 251*32768 = 8224768
static constexpr size_t OFF_S1      = 15194112;        // 65536 (ping-pong)
static constexpr size_t OFF_C1      = 15259648;        // 32768
static constexpr size_t OFF_C2      = 15292416;        // 32768
static constexpr size_t OFF_CUM     = 15325184;        // 8192 (6400 used)
static constexpr size_t OFF_DPART   = 15333376;        // 32768 (32*8*128)
static constexpr size_t OFF_SC      = 15366144;        // 8192 (6400 used)
static constexpr size_t OFF_P1      = 15390720;        // 14*32*4096 = 1835008
static constexpr size_t OFF_P2      = 17225728;        // 16*32*4096 = 2097152

// d_out offsets (floats)
static constexpr size_t OUT_TOK  = 1280000;
static constexpr size_t OUT_ATTN = 1296000;

// ---------------------------------------------------------------------------
// Threefry-2x32 (JAX partitionable split — verified bit-exact)
// ---------------------------------------------------------------------------
__device__ __forceinline__ uint2 threefry(unsigned k0, unsigned k1, unsigned c0, unsigned c1) {
  unsigned ks2 = k0 ^ k1 ^ 0x1BD11BDAu;
  unsigned x0 = c0 + k0, x1 = c1 + k1;
#define TFR(rot) { x0 += x1; x1 = (x1 << (rot)) | (x1 >> (32 - (rot))); x1 ^= x0; }
  TFR(13) TFR(15) TFR(26) TFR(6)   x0 += k1;  x1 += ks2 + 1u;
  TFR(17) TFR(29) TFR(16) TFR(24)  x0 += ks2; x1 += k0 + 2u;
  TFR(13) TFR(15) TFR(26) TFR(6)   x0 += k0;  x1 += k1 + 3u;
  TFR(17) TFR(29) TFR(16) TFR(24)  x0 += k1;  x1 += ks2 + 4u;
  TFR(13) TFR(15) TFR(26) TFR(6)   x0 += ks2; x1 += k0 + 5u;
#undef TFR
  return make_uint2(x0, x1);
}

__device__ __forceinline__ float u32_to_uniform(unsigned b) {
  return __uint_as_float((b >> 9) | 0x3f800000u) - 1.0f;
}

__device__ __forceinline__ float rng_uniform(unsigned k0, unsigned k1, unsigned i) {
  uint2 h = threefry(k0, k1, 0u, i);
  return u32_to_uniform(h.x ^ h.y);
}

__device__ __forceinline__ float gatef(float x) { return tanhf(x * 0.5f) * 0.5f + 0.5f; }

#define FMA4(A, S, W) { (A).x = fmaf((S), (W).x, (A).x); (A).y = fmaf((S), (W).y, (A).y); \
                        (A).z = fmaf((S), (W).z, (A).z); (A).w = fmaf((S), (W).w, (A).w); }

// ---------------------------------------------------------------------------
// k_init: zero states + cum + dpart, attn rows 250..499, RNG keys, CWt.
// ---------------------------------------------------------------------------
__global__ __launch_bounds__(256) void k_init(float* __restrict__ ws, float* __restrict__ out,
                                              const float* __restrict__ conv_w,
                                              const float* __restrict__ Wcp) {
  const size_t NZERO1 = 172032;   // s1(2x)+c1+c2+cum+dpart contiguous at OFF_S1
  const size_t NZERO2 = 32768;    // s2_all slot 0
  const size_t NATTN  = 1600000;  // attn rows 250..499
  const size_t NKEYS  = 250;
  const size_t NCWT   = 4096;
  const size_t TOTAL  = NZERO1 + NZERO2 + NATTN + NKEYS + NCWT;
  unsigned* keys = (unsigned*)(ws + OFF_KEYS);
  for (size_t i = (size_t)blockIdx.x * 256 + threadIdx.x; i < TOTAL; i += (size_t)gridDim.x * 256) {
    if (i < NZERO1) {
      ws[OFF_S1 + i] = 0.f;
    } else if (i < NZERO1 + NZERO2) {
      ws[OFF_S2 + (i - NZERO1)] = 0.f;
    } else if (i < NZERO1 + NZERO2 + NATTN) {
      size_t r = i - NZERO1 - NZERO2;
      size_t b = r / 50000, rem = r % 50000;
      out[OUT_ATTN + b * 100000 + 50000 + rem] = 0.f;
    } else if (i < NZERO1 + NZERO2 + NATTN + NKEYS) {
      int s = (int)(i - NZERO1 - NZERO2 - NATTN);
      uint2 F = threefry(0u, 1234u, 0u, (unsigned)s);
      uint2 kd1 = threefry(F.x, F.y, 0u, 0u);
      uint2 kd2 = threefry(F.x, F.y, 0u, 1u);
      uint2 kz1 = threefry(F.x, F.y, 0u, 2u);
      uint2 kz2 = threefry(F.x, F.y, 0u, 3u);
      keys[s * 8 + 0] = kd1.x; keys[s * 8 + 1] = kd1.y;
      keys[s * 8 + 2] = kd2.x; keys[s * 8 + 3] = kd2.y;
      keys[s * 8 + 4] = kz1.x; keys[s * 8 + 5] = kz1.y;
      keys[s * 8 + 6] = kz2.x; keys[s * 8 + 7] = kz2.y;
    } else {
      size_t r = i - NZERO1 - NZERO2 - NATTN - NKEYS;   // [0,4096)
      int a = (int)(r >> 5), kk = (int)(r & 31);
      float v = 0.f;
      if (kk < 31) {
        for (int f = 0; f < 32; ++f) v = fmaf(conv_w[f * 31 + kk], Wcp[f * 128 + a], v);
      }
      ws[OFF_CWT + r] = v;   // CWt[a][k], row stride 32
    }
  }
}

// ---------------------------------------------------------------------------
// k_encproj: encproj = e_outputs @ W_encproj + b  ([6400,512]@[512,128])
// ---------------------------------------------------------------------------
__global__ __launch_bounds__(256) void k_encproj(const float* __restrict__ e_out,
                                                 const float* __restrict__ Wenc,
                                                 const float* __restrict__ benc,
                                                 float* __restrict__ encproj) {
  __shared__ __align__(16) float xs[32 * 516];
  int t = threadIdx.x;
  int r0 = blockIdx.x * 32;
  for (int i = 0; i < 64; ++i) {
    int idx = t + 256 * i; int rb = idx >> 9, kk = idx & 511;
    xs[rb * 516 + kk] = e_out[(size_t)(r0 + rb) * 512 + kk];
  }
  __syncthreads();
  int a = t & 127, rh = t >> 7;
  float acc[16];
#pragma unroll
  for (int r = 0; r < 16; ++r) acc[r] = 0.f;
  const float4* xv = (const float4*)xs;
  for (int k4 = 0; k4 < 128; ++k4) {
    const float* wp = Wenc + (size_t)(k4 * 4) * 128 + a;
    float w0 = wp[0], w1 = wp[128], w2 = wp[256], w3 = wp[384];
#pragma unroll
    for (int r = 0; r < 16; ++r) {
      float4 x4 = xv[(rh * 16 + r) * 129 + k4];
      acc[r] = fmaf(x4.x, w0, acc[r]); acc[r] = fmaf(x4.y, w1, acc[r]);
      acc[r] = fmaf(x4.z, w2, acc[r]); acc[r] = fmaf(x4.w, w3, acc[r]);
    }
  }
  float bb = benc[a];
  for (int r = 0; r < 16; ++r)
    encproj[(size_t)(r0 + rh * 16 + r) * 128 + a] = acc[r] + bb;
}

// ---------------------------------------------------------------------------
// k_prenet: all 250 steps, exact dropout
// ---------------------------------------------------------------------------
__global__ __launch_bounds__(256) void k_prenet(const float* __restrict__ mel,
                                                const float* __restrict__ W1, const float* __restrict__ b1,
                                                const float* __restrict__ W2, const float* __restrict__ b2,
                                                const unsigned* __restrict__ keys,
                                                float* __restrict__ pre2_all) {
  int s = blockIdx.x, t = threadIdx.x;
  __shared__ __align__(16) float prev[32 * 80];
  __shared__ __align__(16) float p1[32 * 256];
  for (int i = 0; i < 10; ++i) {
    int idx = t + 256 * i;
    int bb = idx / 80, vv = idx % 80;
    prev[idx] = (s == 0) ? 0.f : mel[(size_t)bb * 40000 + (size_t)(2 * s - 1) * 80 + vv];
  }
  __syncthreads();
  unsigned kd10 = keys[s * 8 + 0], kd11 = keys[s * 8 + 1];
  unsigned kd20 = keys[s * 8 + 2], kd21 = keys[s * 8 + 3];
  float acc[32];
  float bias = b1[t];
#pragma unroll
  for (int b = 0; b < 32; ++b) acc[b] = bias;
  for (int k4 = 0; k4 < 20; ++k4) {
    const float* wp = W1 + (size_t)(k4 * 4) * 256 + t;
    float w0 = wp[0], w1 = wp[256], w2 = wp[512], w3 = wp[768];
#pragma unroll
    for (int b = 0; b < 32; ++b) {
      float4 x4 = *(const float4*)(prev + b * 80 + k4 * 4);
      acc[b] = fmaf(x4.x, w0, acc[b]); acc[b] = fmaf(x4.y, w1, acc[b]);
      acc[b] = fmaf(x4.z, w2, acc[b]); acc[b] = fmaf(x4.w, w3, acc[b]);
    }
  }
#pragma unroll
  for (int b = 0; b < 32; ++b) {
    float r = fmaxf(acc[b], 0.f);
    float u = rng_uniform(kd10, kd11, (unsigned)(b * 256 + t));
    p1[b * 256 + t] = (u < 0.5f) ? r * 2.f : 0.f;
  }
  __syncthreads();
  float bias2 = b2[t];
#pragma unroll
  for (int b = 0; b < 32; ++b) acc[b] = bias2;
  for (int k4 = 0; k4 < 64; ++k4) {
    const float* wp = W2 + (size_t)(k4 * 4) * 256 + t;
    float w0 = wp[0], w1 = wp[256], w2 = wp[512], w3 = wp[768];
#pragma unroll
    for (int b = 0; b < 32; ++b) {
      float4 x4 = *(const float4*)(p1 + b * 256 + k4 * 4);
      acc[b] = fmaf(x4.x, w0, acc[b]); acc[b] = fmaf(x4.y, w1, acc[b]);
      acc[b] = fmaf(x4.z, w2, acc[b]); acc[b] = fmaf(x4.w, w3, acc[b]);
    }
  }
  for (int b = 0; b < 32; ++b) {
    float r = fmaxf(acc[b], 0.f);
    float u = rng_uniform(kd20, kd21, (unsigned)(b * 256 + t));
    pre2_all[(size_t)(s * 32 + b) * 256 + t] = (u < 0.5f) ? r * 2.f : 0.f;
  }
}

// ---------------------------------------------------------------------------
// Phase bodies (shared by standalone kernels and the cooperative loop).
// All are exact transcriptions of the round-5 kernels with blockIdx -> u.
// Leading __syncthreads() guards LDS reuse across grid-stride iterations.
// ---------------------------------------------------------------------------
__device__ __forceinline__ void ph_escore(int u,
    const float* __restrict__ dpart, const float* __restrict__ encproj,
    const float* __restrict__ cwt, const float* __restrict__ cum,
    const float* __restrict__ Wself, float* __restrict__ sglob) {
  __shared__ float dp[128];
  __shared__ float ca[232];
  __shared__ float scpart[4];
  int b = u & 31, p = u >> 5;
  int t = threadIdx.x;
  __syncthreads();
  if (t < 128) {
    float acc = 0.f;
#pragma unroll
    for (int q = 0; q < 8; ++q) acc += dpart[(b * 8 + q) * 128 + t];
    dp[t] = acc;
  }
  if (t < 232) ca[t] = (t >= 15 && t < 215) ? cum[b * 200 + (t - 15)] : 0.f;
  __syncthreads();
  int a = t & 127, lh = t >> 7;
  float cwr[31];
#pragma unroll
  for (int k = 0; k < 31; ++k) cwr[k] = cwt[a * 32 + k];
  float wself = Wself[a];
  float dpr = dp[a];
  for (int ii = 0; ii < 13; ++ii) {
    int lo = ii * 2 + lh;
    int l = p * 25 + lo;
    float v = 0.f;
    if (lo < 25) {
      float conv = 0.f;
#pragma unroll
      for (int k = 0; k < 31; ++k) conv = fmaf(ca[l + k], cwr[k], conv);
      float e = tanhf(dpr + encproj[(size_t)(b * 200 + l) * 128 + a] + conv);
      v = e * wself;
    }
#pragma unroll
    for (int off = 32; off > 0; off >>= 1) v += __shfl_xor(v, off, 64);
    if ((t & 63) == 0) scpart[t >> 6] = v;
    __syncthreads();
    if (t == 0) sglob[b * 200 + p * 25 + ii * 2] = scpart[0] + scpart[1];
    if (t == 128 && ii < 12) sglob[b * 200 + p * 25 + ii * 2 + 1] = scpart[2] + scpart[3];
    __syncthreads();
  }
}

__device__ __forceinline__ void ph_attng(int u,
    const float* __restrict__ sglob, const float* __restrict__ e_out,
    float* __restrict__ cum, float* __restrict__ g_out,
    float* __restrict__ attn_out) {
  __shared__ float sc[200];
  __shared__ float red[8];
  __shared__ float bcv[2];
  __shared__ float gpart[4][64];
  int b = u & 31, p = u >> 5;
  int t = threadIdx.x;
  __syncthreads();
  if (t < 200) sc[t] = sglob[b * 200 + t];
  __syncthreads();
  float v = (t < 200) ? sc[t] : -3.4e38f;
#pragma unroll
  for (int off = 32; off > 0; off >>= 1) v = fmaxf(v, __shfl_xor(v, off, 64));
  if ((t & 63) == 0) red[t >> 6] = v;
  __syncthreads();
  if (t == 0) bcv[0] = fmaxf(fmaxf(red[0], red[1]), fmaxf(red[2], red[3]));
  __syncthreads();
  float mx = bcv[0];
  float ex = (t < 200) ? expf(sc[t] - mx) : 0.f;
  float sv = ex;
#pragma unroll
  for (int off = 32; off > 0; off >>= 1) sv += __shfl_xor(sv, off, 64);
  if ((t & 63) == 0) red[4 + (t >> 6)] = sv;
  __syncthreads();
  if (t == 0) bcv[1] = (red[4] + red[5]) + (red[6] + red[7]);
  __syncthreads();
  float denom = bcv[1];
  if (t < 200) {
    float al = ex / denom;
    sc[t] = al;
    if (p == 0) {
      cum[b * 200 + t] += al;
      attn_out[(size_t)b * 100000 + t] = al;
    }
  }
  __syncthreads();
  int d = p * 64 + (t & 63), lq = t >> 6;
  const float* eb = e_out + (size_t)b * 102400 + d;
  float acc = 0.f;
  for (int l = lq * 50; l < lq * 50 + 50; ++l) acc = fmaf(sc[l], eb[(size_t)l * 512], acc);
  gpart[lq][t & 63] = acc;
  __syncthreads();
  if (t < 64)
    g_out[b * 512 + p * 64 + t] = (gpart[0][t] + gpart[1][t]) + (gpart[2][t] + gpart[3][t]);
}

__device__ __forceinline__ void gemm_body(
    const float* __restrict__ W0, int k0,
    float* __restrict__ part, int c, int jt,
    const float* __restrict__ xs /*staged 32x132*/) {
  int t = threadIdx.x;
  int jq = t & 31, bq = t >> 5;
  int j = jt * 32 + jq;
  float4 acc[4];
  acc[0] = acc[1] = acc[2] = acc[3] = make_float4(0, 0, 0, 0);
  const float4* xv = (const float4*)xs;
  const float* Wb = W0 + (size_t)k0 * 4096 + j;
#pragma unroll 4
  for (int k4 = 0; k4 < 32; ++k4) {
    float4 xq[4];
    xq[0] = xv[(bq * 4 + 0) * 33 + k4];
    xq[1] = xv[(bq * 4 + 1) * 33 + k4];
    xq[2] = xv[(bq * 4 + 2) * 33 + k4];
    xq[3] = xv[(bq * 4 + 3) * 33 + k4];
    const float* wr = Wb + (size_t)(k4 * 4) * 4096;
#pragma unroll
    for (int ks = 0; ks < 4; ++ks) {
      float wi = wr[0], wf = wr[1024], wc = wr[2048], wo = wr[3072];
      wr += 4096;
#pragma unroll
      for (int r = 0; r < 4; ++r) {
        float xval = ((const float*)&xq[r])[ks];
        acc[r].x = fmaf(xval, wi, acc[r].x);
        acc[r].y = fmaf(xval, wf, acc[r].y);
        acc[r].z = fmaf(xval, wc, acc[r].z);
        acc[r].w = fmaf(xval, wo, acc[r].w);
      }
    }
  }
  float* pb = part + (size_t)c * 131072 + (size_t)(bq * 4) * 4096 + j;
#pragma unroll
  for (int r = 0; r < 4; ++r) {
    float* pr = pb + r * 4096;
    pr[0] = acc[r].x; pr[1024] = acc[r].y; pr[2048] = acc[r].z; pr[3072] = acc[r].w;
  }
}

__device__ __forceinline__ void ph_b1g(int u,
    const float* __restrict__ pre2_s, const float* __restrict__ s1old,
    const float* __restrict__ g_s,
    const float* __restrict__ Wys, const float* __restrict__ Wss, const float* __restrict__ Wgs,
    float* __restrict__ part) {
  __shared__ __align__(16) float xs[32 * 132];
  int t = threadIdx.x;
  int jt = u & 31, c = u >> 5;   // c in 0..13
  __syncthreads();
  {
    int r = t >> 3, kq = t & 7;
    const float* src;
    if (c < 2)       src = pre2_s + r * 256 + c * 128;
    else if (c < 10) src = s1old + r * 1024 + (c - 2) * 128;
    else             src = g_s + r * 512 + (c - 10) * 128;
    const float4* s4 = (const float4*)(src + kq * 16);
    float4* d4 = (float4*)(xs + r * 132 + kq * 16);
    d4[0] = s4[0]; d4[1] = s4[1]; d4[2] = s4[2]; d4[3] = s4[3];
  }
  const float* W0; int k0;
  if (c < 2)       { W0 = Wys; k0 = c * 128; }
  else if (c < 10) { W0 = Wss; k0 = (c - 2) * 128; }
  else             { W0 = Wgs; k0 = (c - 10) * 128; }
  __syncthreads();
  gemm_body(W0, k0, part, c, jt, xs);
}

__device__ __forceinline__ void ph_b2g(int u,
    const float* __restrict__ s1new, const float* __restrict__ s2prev,
    const float* __restrict__ Wis, const float* __restrict__ Wss2,
    float* __restrict__ part) {
  __shared__ __align__(16) float xs[32 * 132];
  int t = threadIdx.x;
  int jt = u & 31, c = u >> 5;   // c in 0..15
  __syncthreads();
  {
    int r = t >> 3, kq = t & 7;
    const float* src = (c < 8) ? (s1new + r * 1024 + c * 128)
                               : (s2prev + r * 1024 + (c - 8) * 128);
    const float4* s4 = (const float4*)(src + kq * 16);
    float4* d4 = (float4*)(xs + r * 132 + kq * 16);
    d4[0] = s4[0]; d4[1] = s4[1]; d4[2] = s4[2]; d4[3] = s4[3];
  }
  const float* W0; int k0;
  if (c < 8) { W0 = Wis;  k0 = c * 128; }
  else       { W0 = Wss2; k0 = (c - 8) * 128; }
  __syncthreads();
  gemm_body(W0, k0, part, c, jt, xs);
}

__device__ __forceinline__ void ph_cell1(int u,
    const float* __restrict__ part, const float* __restrict__ bias,
    const float* __restrict__ sold, float* __restrict__ snew, float* __restrict__ cst,
    const unsigned* __restrict__ keyp) {
  int e = u * 256 + threadIdx.x;   // [0, 32768)
  int b = e >> 10, j = e & 1023;
  float gi = bias[j], gf = bias[1024 + j], gc = bias[2048 + j], go = bias[3072 + j];
  const float* pc = part + (size_t)b * 4096 + j;
#pragma unroll
  for (int cc = 0; cc < 14; ++cc) {
    const float* p2 = pc + (size_t)cc * 131072;
    gi += p2[0]; gf += p2[1024]; gc += p2[2048]; go += p2[3072];
  }
  float u1 = rng_uniform(keyp[0], keyp[1], (unsigned)e);
  float m = floorf(u1 + 0.1f);
  float co = cst[e], so = sold[e];
  float cn = fmaf(gatef(gf), co, gatef(gi) * tanhf(gc));
  float cnew = (m > 0.5f) ? co : cn;
  float sn = (m > 0.5f) ? so : (gatef(go) * tanhf(cnew));
  cst[e] = cnew;
  snew[e] = sn;
}

__device__ __forceinline__ void ph_cell2dp(int u,
    const float* __restrict__ part, const float* __restrict__ bias,
    const float* __restrict__ sold, float* __restrict__ snew, float* __restrict__ cst,
    const unsigned* __restrict__ keyp,
    const float* __restrict__ Wdec, float* __restrict__ dpart) {
  __shared__ float s2l[128];
  __shared__ float dtmp[256];
  int b = u & 31, p = u >> 5;
  int t = threadIdx.x;
  __syncthreads();
  if (t < 128) {
    int j = p * 128 + t;
    int e = b * 1024 + j;
    float gi = bias[j], gf = bias[1024 + j], gc = bias[2048 + j], go = bias[3072 + j];
    const float* pc = part + (size_t)b * 4096 + j;
#pragma unroll
    for (int cc = 0; cc < 16; ++cc) {
      const float* p2 = pc + (size_t)cc * 131072;
      gi += p2[0]; gf += p2[1024]; gc += p2[2048]; go += p2[3072];
    }
    float u1 = rng_uniform(keyp[0], keyp[1], (unsigned)e);
    float m = floorf(u1 + 0.1f);
    float co = cst[e], so = sold[e];
    float cn = fmaf(gatef(gf), co, gatef(gi) * tanhf(gc));
    float cnew = (m > 0.5f) ? co : cn;
    float sn = (m > 0.5f) ? so : (gatef(go) * tanhf(cnew));
    cst[e] = cnew;
    snew[e] = sn;
    s2l[t] = sn;
  }
  __syncthreads();
  int a = t & 127, h = t >> 7;
  const float* wp = Wdec + (size_t)(p * 128 + h * 64) * 128 + a;
  float acc = 0.f;
#pragma unroll 8
  for (int r = 0; r < 64; ++r) acc = fmaf(s2l[h * 64 + r], wp[(size_t)r * 128], acc);
  dtmp[t] = acc;
  __syncthreads();
  if (t < 128) dpart[(b * 8 + p) * 128 + t] = dtmp[t] + dtmp[t + 128];
}

// ---------------------------------------------------------------------------
// Standalone kernels (fallback path = exact round-5 sequence)
// ---------------------------------------------------------------------------
__global__ __launch_bounds__(256) void k_escore(const float* __restrict__ dpart,
                                                const float* __restrict__ encproj,
                                                const float* __restrict__ cwt,
                                                const float* __restrict__ cum,
                                                const float* __restrict__ Wself,
                                                float* __restrict__ sglob) {
  ph_escore(blockIdx.x, dpart, encproj, cwt, cum, Wself, sglob);
}

__global__ __launch_bounds__(256) void k_attng(const float* __restrict__ sglob,
                                               const float* __restrict__ e_out,
                                               float* __restrict__ cum,
                                               float* __restrict__ g_out,
                                               float* __restrict__ attn_out) {
  ph_attng(blockIdx.x, sglob, e_out, cum, g_out, attn_out);
}

__global__ __launch_bounds__(256) void k_b1g(
    const float* __restrict__ pre2_s, const float* __restrict__ s1old,
    const float* __restrict__ g_s,
    const float* __restrict__ Wys, const float* __restrict__ Wss, const float* __restrict__ Wgs,
    float* __restrict__ part) {
  ph_b1g(blockIdx.x, pre2_s, s1old, g_s, Wys, Wss, Wgs, part);
}

__global__ __launch_bounds__(256) void k_b2g(
    const float* __restrict__ s1new, const float* __restrict__ s2prev,
    const float* __restrict__ Wis, const float* __restrict__ Wss2,
    float* __restrict__ part) {
  ph_b2g(blockIdx.x, s1new, s2prev, Wis, Wss2, part);
}

__global__ __launch_bounds__(256) void k_cell1(
    const float* __restrict__ part, const float* __restrict__ bias,
    const float* __restrict__ sold, float* __restrict__ snew, float* __restrict__ cst,
    const unsigned* __restrict__ keyp) {
  ph_cell1(blockIdx.x, part, bias, sold, snew, cst, keyp);
}

__global__ __launch_bounds__(256) void k_cell2dp(
    const float* __restrict__ part, const float* __restrict__ bias,
    const float* __restrict__ sold, float* __restrict__ snew, float* __restrict__ cst,
    const unsigned* __restrict__ keyp,
    const float* __restrict__ Wdec, float* __restrict__ dpart) {
  ph_cell2dp(blockIdx.x, part, bias, sold, snew, cst, keyp, Wdec, dpart);
}

// ---------------------------------------------------------------------------
// Persistent cooperative loop kernel: 250 steps x 6 phases, grid.sync between.
// Grid-strided phases so any co-resident grid >= 1 works (launch tries 512).
// ---------------------------------------------------------------------------
struct LoopArgs {
  const float* e_out;
  const float* Wdec; const float* Wself;
  const float* Wys; const float* Wss; const float* Wgs; const float* bgs;
  const float* Wis; const float* Wss2; const float* bss2;
  float* ws; float* out;
};

__global__ __launch_bounds__(256, 2) void k_loop(LoopArgs a) {
  cg::grid_group grid = cg::this_grid();
  float* ws = a.ws;
  const unsigned* keys = (const unsigned*)(ws + OFF_KEYS);
  const int nb = (int)gridDim.x;
  for (int s = 0; s < NSTEP; ++s) {
    float* s1old = ws + OFF_S1 + (size_t)(s & 1) * 32768;
    float* s1new = ws + OFF_S1 + (size_t)((s + 1) & 1) * 32768;
    float* s2s   = ws + OFF_S2 + (size_t)s * 32768;
    float* s2n   = ws + OFF_S2 + (size_t)(s + 1) * 32768;
    float* gs    = ws + OFF_G  + (size_t)s * 16384;

    for (int u = blockIdx.x; u < 256; u += nb)
      ph_escore(u, ws + OFF_DPART, ws + OFF_ENCPROJ, ws + OFF_CWT, ws + OFF_CUM,
                a.Wself, ws + OFF_SC);
    grid.sync();
    for (int u = blockIdx.x; u < 256; u += nb)
      ph_attng(u, ws + OFF_SC, a.e_out, ws + OFF_CUM, gs,
               a.out + OUT_ATTN + (size_t)s * 200);
    grid.sync();
    for (int u = blockIdx.x; u < 448; u += nb)
      ph_b1g(u, ws + OFF_PRE2 + (size_t)s * 8192, s1old, gs, a.Wys, a.Wss, a.Wgs,
             ws + OFF_P1);
    grid.sync();
    for (int u = blockIdx.x; u < 128; u += nb)
      ph_cell1(u, ws + OFF_P1, a.bgs, s1old, s1new, ws + OFF_C1, keys + s * 8 + 4);
    grid.sync();
    for (int u = blockIdx.x; u < 512; u += nb)
      ph_b2g(u, s1new, s2s, a.Wis, a.Wss2, ws + OFF_P2);
    grid.sync();
    for (int u = blockIdx.x; u < 256; u += nb)
      ph_cell2dp(u, ws + OFF_P2, a.bss2, s2s, s2n, ws + OFF_C2, keys + s * 8 + 6,
                 a.Wdec, ws + OFF_DPART);
    grid.sync();
  }
}

// ---------------------------------------------------------------------------
// k_frame: deferred frame/token projection. grid 250.
// ---------------------------------------------------------------------------
__global__ __launch_bounds__(256) void k_frame(const float* __restrict__ s2_all,
                                               const float* __restrict__ g_all,
                                               const float* __restrict__ Wf,
                                               const float* __restrict__ bf,
                                               const float* __restrict__ Wt,
                                               const float* __restrict__ bt,
                                               float* __restrict__ out_frame,
                                               float* __restrict__ out_tok) {
  int s = blockIdx.x, t = threadIdx.x;
  __shared__ __align__(16) float xs[32 * 516];
  int b = t >> 3, ci = t & 7;
  int tb = t >> 1, tr = t & 1;
  float4 acc[5];
#pragma unroll
  for (int r = 0; r < 5; ++r) acc[r] = make_float4(0, 0, 0, 0);
  float tok = 0.f;
  for (int ch = 0; ch < 3; ++ch) {
    for (int i = 0; i < 64; ++i) {
      int idx = t + 256 * i;
      int rb = idx >> 9, kk = idx & 511;
      float vsrc = (ch < 2) ? s2_all[(size_t)(s + 1) * 32768 + rb * 1024 + ch * 512 + kk]
                            : g_all[(size_t)s * 16384 + rb * 512 + kk];
      xs[rb * 516 + kk] = vsrc;
    }
    __syncthreads();
    const float4* xv = (const float4*)xs;
    for (int k4 = 0; k4 < 128; ++k4) {
      float4 x4 = xv[b * 129 + k4];
      int kglob = ch * 512 + k4 * 4;
#pragma unroll
      for (int rep = 0; rep < 5; ++rep) {
        int c4 = ci * 4 + rep * 32;
        const float* wrow = Wf + (size_t)kglob * 160 + c4;
        float4 w0 = *(const float4*)(wrow);
        float4 w1 = *(const float4*)(wrow + 160);
        float4 w2 = *(const float4*)(wrow + 320);
        float4 w3 = *(const float4*)(wrow + 480);
        FMA4(acc[rep], x4.x, w0); FMA4(acc[rep], x4.y, w1);
        FMA4(acc[rep], x4.z, w2); FMA4(acc[rep], x4.w, w3);
      }
      if (t < 64) {
        float4 xt = xv[tb * 129 + k4];
        tok = fmaf(xt.x, Wt[(size_t)(kglob + 0) * 2 + tr], tok);
        tok = fmaf(xt.y, Wt[(size_t)(kglob + 1) * 2 + tr], tok);
        tok = fmaf(xt.z, Wt[(size_t)(kglob + 2) * 2 + tr], tok);
        tok = fmaf(xt.w, Wt[(size_t)(kglob + 3) * 2 + tr], tok);
      }
    }
    __syncthreads();
  }
#pragma unroll
  for (int rep = 0; rep < 5; ++rep) {
    float vals[4] = {acc[rep].x, acc[rep].y, acc[rep].z, acc[rep].w};
#pragma unroll
    for (int jj = 0; jj < 4; ++jj) {
      int cc = ci * 4 + rep * 32 + jj;
      float val = vals[jj] + bf[cc];
      int row = 2 * s + (cc >= 80 ? 1 : 0);
      int col = cc - (cc >= 80 ? 80 : 0);
      out_frame[(size_t)b * 40000 + (size_t)row * 80 + col] = val;
    }
  }
  if (t < 64) out_tok[(size_t)tb * 500 + 2 * s + tr] = tok + bt[tr];
}

// ---------------------------------------------------------------------------
extern "C" void kernel_launch(void* const* d_in, const int* in_sizes, int n_in,
                              void* d_out_v, int out_size, void* d_ws, size_t ws_size,
                              hipStream_t stream) {
  (void)in_sizes; (void)n_in; (void)out_size; (void)ws_size;
  const float* mel      = (const float*)d_in[0];
  const float* e_out    = (const float*)d_in[1];
  const float* conv_w   = (const float*)d_in[2];
  const float* Wcp      = (const float*)d_in[3];
  const float* Wenc     = (const float*)d_in[4];
  const float* benc     = (const float*)d_in[5];
  const float* Wdec     = (const float*)d_in[6];
  const float* Wself    = (const float*)d_in[7];
  const float* Wp1      = (const float*)d_in[8];
  const float* bp1      = (const float*)d_in[9];
  const float* Wp2      = (const float*)d_in[10];
  const float* bp2      = (const float*)d_in[11];
  const float* Wys      = (const float*)d_in[12];
  const float* Wss      = (const float*)d_in[13];
  const float* Wgs      = (const float*)d_in[14];
  const float* bgs      = (const float*)d_in[15];
  const float* Wis      = (const float*)d_in[16];
  const float* Wss2     = (const float*)d_in[17];
  const float* bss2     = (const float*)d_in[18];
  const float* Wf       = (const float*)d_in[19];
  const float* bf       = (const float*)d_in[20];
  const float* Wt       = (const float*)d_in[21];
  const float* bt       = (const float*)d_in[22];
  float* ws  = (float*)d_ws;
  float* out = (float*)d_out_v;
  const unsigned* keys = (const unsigned*)(ws + OFF_KEYS);

  hipLaunchKernelGGL(k_init, dim3(1024), dim3(256), 0, stream, ws, out, conv_w, Wcp);
  hipLaunchKernelGGL(k_encproj, dim3(200), dim3(256), 0, stream, e_out, Wenc, benc, ws + OFF_ENCPROJ);
  hipLaunchKernelGGL(k_prenet, dim3(250), dim3(256), 0, stream, mel, Wp1, bp1, Wp2, bp2, keys, ws + OFF_PRE2);

  LoopArgs la{e_out, Wdec, Wself, Wys, Wss, Wgs, bgs, Wis, Wss2, bss2, ws, out};
  void* kargs[] = { (void*)&la };
  hipError_t ce = hipLaunchCooperativeKernel(
      reinterpret_cast<const void*>(k_loop), dim3(512), dim3(256), kargs, 0, stream);
  if (ce != hipSuccess) {
    (void)hipGetLastError();
    ce = hipLaunchCooperativeKernel(
        reinterpret_cast<const void*>(k_loop), dim3(256), dim3(256), kargs, 0, stream);
  }
  if (ce != hipSuccess) {
    (void)hipGetLastError();
    // Fallback: exact round-5 six-kernel sequence (verified 15.5 ms).
    for (int s = 0; s < NSTEP; ++s) {
      float* s1old = ws + OFF_S1 + (size_t)(s & 1) * 32768;
      float* s1new = ws + OFF_S1 + (size_t)((s + 1) & 1) * 32768;
      float* s2s   = ws + OFF_S2 + (size_t)s * 32768;
      float* s2n   = ws + OFF_S2 + (size_t)(s + 1) * 32768;
      float* gs    = ws + OFF_G  + (size_t)s * 16384;
      hipLaunchKernelGGL(k_escore, dim3(256), dim3(256), 0, stream,
                         ws + OFF_DPART, ws + OFF_ENCPROJ, ws + OFF_CWT, ws + OFF_CUM,
                         Wself, ws + OFF_SC);
      hipLaunchKernelGGL(k_attng, dim3(256), dim3(256), 0, stream,
                         ws + OFF_SC, e_out, ws + OFF_CUM, gs,
                         out + OUT_ATTN + (size_t)s * 200);
      hipLaunchKernelGGL(k_b1g, dim3(448), dim3(256), 0, stream,
                         ws + OFF_PRE2 + (size_t)s * 8192, s1old, gs, Wys, Wss, Wgs,
                         ws + OFF_P1);
      hipLaunchKernelGGL(k_cell1, dim3(128), dim3(256), 0, stream,
                         ws + OFF_P1, bgs, s1old, s1new, ws + OFF_C1, keys + s * 8 + 4);
      hipLaunchKernelGGL(k_b2g, dim3(512), dim3(256), 0, stream,
                         s1new, s2s, Wis, Wss2, ws + OFF_P2);
      hipLaunchKernelGGL(k_cell2dp, dim3(256), dim3(256), 0, stream,
                         ws + OFF_P2, bss2, s2s, s2n, ws + OFF_C2, keys + s * 8 + 6,
                         Wdec, ws + OFF_DPART);
    }
  }
  hipLaunchKernelGGL(k_frame, dim3(250), dim3(256), 0, stream,
                     ws + OFF_S2, ws + OFF_G, Wf, bf, Wt, bt, out, out + OUT_TOK);
}

// Round 4
// 58938.885 us; speedup vs baseline: 1.7938x; 1.7938x over previous
//
#include <hip/hip_runtime.h>
#include <cstdint>
#include <cstddef>

// ---------------------------------------------------------------------------
// Tacotron2 decoder, MI355X. Round 8: back to round-5 multi-kernel structure
// (R7's cg::grid.sync measured ~70us/sync — dead end). Cut 6->4 kernels/step
// by full-K fusion: each GEMM block owns a 16-gate-col tile across ALL K and
// all 32 batch rows, so the LSTM cell is block-local (no partial buffers):
//   k_escore (256): dp = s2 @ Wdec (exact R5 q-chunk/half order) + conv+score
//   k_attng  (256): softmax + cum + attn + g            [unchanged from R5]
//   k_b1f    (256): full-K LSTM1 GEMM (14 chunks) + cell1 -> s1new
//   k_b2f    (256): full-K LSTM2 GEMM (16 chunks) + cell2 -> s2 slot s+1
// All fp reduction orders replicate R5 bit-exactly (absmax canary 4.8828e-4).
// ---------------------------------------------------------------------------

static constexpr int NSTEP = 250;

// workspace offsets (floats). total = 19,322,880 floats (~77.3 MB)
static constexpr size_t OFF_ENCPROJ = 0;               // 819200
static constexpr size_t OFF_CWT     = 819200;          // 4096
static constexpr size_t OFF_KEYS    = 823296;          // 2048 (250*8 uints)
static constexpr size_t OFF_PRE2    = 825344;          // 2048000
static constexpr size_t OFF_G       = 2873344;         // 4096000
static constexpr size_t OFF_S2      = 6969344;         // 251*32768 = 8224768
static constexpr size_t OFF_S1      = 15194112;        // 65536 (ping-pong)
static constexpr size_t OFF_C1      = 15259648;        // 32768
static constexpr size_t OFF_C2      = 15292416;        // 32768
static constexpr size_t OFF_CUM     = 15325184;        // 8192 (6400 used)
static constexpr size_t OFF_SC      = 15366144;        // 8192 (6400 used)

// d_out offsets (floats)
static constexpr size_t OUT_TOK  = 1280000;
static constexpr size_t OUT_ATTN = 1296000;

// ---------------------------------------------------------------------------
// Threefry-2x32 (JAX partitionable split — verified bit-exact)
// ---------------------------------------------------------------------------
__device__ __forceinline__ uint2 threefry(unsigned k0, unsigned k1, unsigned c0, unsigned c1) {
  unsigned ks2 = k0 ^ k1 ^ 0x1BD11BDAu;
  unsigned x0 = c0 + k0, x1 = c1 + k1;
#define TFR(rot) { x0 += x1; x1 = (x1 << (rot)) | (x1 >> (32 - (rot))); x1 ^= x0; }
  TFR(13) TFR(15) TFR(26) TFR(6)   x0 += k1;  x1 += ks2 + 1u;
  TFR(17) TFR(29) TFR(16) TFR(24)  x0 += ks2; x1 += k0 + 2u;
  TFR(13) TFR(15) TFR(26) TFR(6)   x0 += k0;  x1 += k1 + 3u;
  TFR(17) TFR(29) TFR(16) TFR(24)  x0 += k1;  x1 += ks2 + 4u;
  TFR(13) TFR(15) TFR(26) TFR(6)   x0 += ks2; x1 += k0 + 5u;
#undef TFR
  return make_uint2(x0, x1);
}

__device__ __forceinline__ float u32_to_uniform(unsigned b) {
  return __uint_as_float((b >> 9) | 0x3f800000u) - 1.0f;
}

__device__ __forceinline__ float rng_uniform(unsigned k0, unsigned k1, unsigned i) {
  uint2 h = threefry(k0, k1, 0u, i);
  return u32_to_uniform(h.x ^ h.y);
}

__device__ __forceinline__ float gatef(float x) { return tanhf(x * 0.5f) * 0.5f + 0.5f; }

#define FMA4(A, S, W) { (A).x = fmaf((S), (W).x, (A).x); (A).y = fmaf((S), (W).y, (A).y); \
                        (A).z = fmaf((S), (W).z, (A).z); (A).w = fmaf((S), (W).w, (A).w); }

// ---------------------------------------------------------------------------
// k_init: zero states + cum, attn rows 250..499, RNG keys, CWt precompute.
// ---------------------------------------------------------------------------
__global__ __launch_bounds__(256) void k_init(float* __restrict__ ws, float* __restrict__ out,
                                              const float* __restrict__ conv_w,
                                              const float* __restrict__ Wcp) {
  const size_t NZERO1 = 139264;   // s1(2x)+c1+c2+cum contiguous at OFF_S1
  const size_t NZERO2 = 32768;    // s2_all slot 0
  const size_t NATTN  = 1600000;  // attn rows 250..499
  const size_t NKEYS  = 250;
  const size_t NCWT   = 4096;
  const size_t TOTAL  = NZERO1 + NZERO2 + NATTN + NKEYS + NCWT;
  unsigned* keys = (unsigned*)(ws + OFF_KEYS);
  for (size_t i = (size_t)blockIdx.x * 256 + threadIdx.x; i < TOTAL; i += (size_t)gridDim.x * 256) {
    if (i < NZERO1) {
      ws[OFF_S1 + i] = 0.f;
    } else if (i < NZERO1 + NZERO2) {
      ws[OFF_S2 + (i - NZERO1)] = 0.f;
    } else if (i < NZERO1 + NZERO2 + NATTN) {
      size_t r = i - NZERO1 - NZERO2;
      size_t b = r / 50000, rem = r % 50000;
      out[OUT_ATTN + b * 100000 + 50000 + rem] = 0.f;
    } else if (i < NZERO1 + NZERO2 + NATTN + NKEYS) {
      int s = (int)(i - NZERO1 - NZERO2 - NATTN);
      uint2 F = threefry(0u, 1234u, 0u, (unsigned)s);
      uint2 kd1 = threefry(F.x, F.y, 0u, 0u);
      uint2 kd2 = threefry(F.x, F.y, 0u, 1u);
      uint2 kz1 = threefry(F.x, F.y, 0u, 2u);
      uint2 kz2 = threefry(F.x, F.y, 0u, 3u);
      keys[s * 8 + 0] = kd1.x; keys[s * 8 + 1] = kd1.y;
      keys[s * 8 + 2] = kd2.x; keys[s * 8 + 3] = kd2.y;
      keys[s * 8 + 4] = kz1.x; keys[s * 8 + 5] = kz1.y;
      keys[s * 8 + 6] = kz2.x; keys[s * 8 + 7] = kz2.y;
    } else {
      size_t r = i - NZERO1 - NZERO2 - NATTN - NKEYS;   // [0,4096)
      int a = (int)(r >> 5), kk = (int)(r & 31);
      float v = 0.f;
      if (kk < 31) {
        for (int f = 0; f < 32; ++f) v = fmaf(conv_w[f * 31 + kk], Wcp[f * 128 + a], v);
      }
      ws[OFF_CWT + r] = v;   // CWt[a][k], row stride 32
    }
  }
}

// ---------------------------------------------------------------------------
// k_encproj: encproj = e_outputs @ W_encproj + b  ([6400,512]@[512,128])
// ---------------------------------------------------------------------------
__global__ __launch_bounds__(256) void k_encproj(const float* __restrict__ e_out,
                                                 const float* __restrict__ Wenc,
                                                 const float* __restrict__ benc,
                                                 float* __restrict__ encproj) {
  __shared__ __align__(16) float xs[32 * 516];
  int t = threadIdx.x;
  int r0 = blockIdx.x * 32;
  for (int i = 0; i < 64; ++i) {
    int idx = t + 256 * i; int rb = idx >> 9, kk = idx & 511;
    xs[rb * 516 + kk] = e_out[(size_t)(r0 + rb) * 512 + kk];
  }
  __syncthreads();
  int a = t & 127, rh = t >> 7;
  float acc[16];
#pragma unroll
  for (int r = 0; r < 16; ++r) acc[r] = 0.f;
  const float4* xv = (const float4*)xs;
  for (int k4 = 0; k4 < 128; ++k4) {
    const float* wp = Wenc + (size_t)(k4 * 4) * 128 + a;
    float w0 = wp[0], w1 = wp[128], w2 = wp[256], w3 = wp[384];
#pragma unroll
    for (int r = 0; r < 16; ++r) {
      float4 x4 = xv[(rh * 16 + r) * 129 + k4];
      acc[r] = fmaf(x4.x, w0, acc[r]); acc[r] = fmaf(x4.y, w1, acc[r]);
      acc[r] = fmaf(x4.z, w2, acc[r]); acc[r] = fmaf(x4.w, w3, acc[r]);
    }
  }
  float bb = benc[a];
  for (int r = 0; r < 16; ++r)
    encproj[(size_t)(r0 + rh * 16 + r) * 128 + a] = acc[r] + bb;
}

// ---------------------------------------------------------------------------
// k_prenet: all 250 steps, exact dropout
// ---------------------------------------------------------------------------
__global__ __launch_bounds__(256) void k_prenet(const float* __restrict__ mel,
                                                const float* __restrict__ W1, const float* __restrict__ b1,
                                                const float* __restrict__ W2, const float* __restrict__ b2,
                                                const unsigned* __restrict__ keys,
                                                float* __restrict__ pre2_all) {
  int s = blockIdx.x, t = threadIdx.x;
  __shared__ __align__(16) float prev[32 * 80];
  __shared__ __align__(16) float p1[32 * 256];
  for (int i = 0; i < 10; ++i) {
    int idx = t + 256 * i;
    int bb = idx / 80, vv = idx % 80;
    prev[idx] = (s == 0) ? 0.f : mel[(size_t)bb * 40000 + (size_t)(2 * s - 1) * 80 + vv];
  }
  __syncthreads();
  unsigned kd10 = keys[s * 8 + 0], kd11 = keys[s * 8 + 1];
  unsigned kd20 = keys[s * 8 + 2], kd21 = keys[s * 8 + 3];
  float acc[32];
  float bias = b1[t];
#pragma unroll
  for (int b = 0; b < 32; ++b) acc[b] = bias;
  for (int k4 = 0; k4 < 20; ++k4) {
    const float* wp = W1 + (size_t)(k4 * 4) * 256 + t;
    float w0 = wp[0], w1 = wp[256], w2 = wp[512], w3 = wp[768];
#pragma unroll
    for (int b = 0; b < 32; ++b) {
      float4 x4 = *(const float4*)(prev + b * 80 + k4 * 4);
      acc[b] = fmaf(x4.x, w0, acc[b]); acc[b] = fmaf(x4.y, w1, acc[b]);
      acc[b] = fmaf(x4.z, w2, acc[b]); acc[b] = fmaf(x4.w, w3, acc[b]);
    }
  }
#pragma unroll
  for (int b = 0; b < 32; ++b) {
    float r = fmaxf(acc[b], 0.f);
    float u = rng_uniform(kd10, kd11, (unsigned)(b * 256 + t));
    p1[b * 256 + t] = (u < 0.5f) ? r * 2.f : 0.f;
  }
  __syncthreads();
  float bias2 = b2[t];
#pragma unroll
  for (int b = 0; b < 32; ++b) acc[b] = bias2;
  for (int k4 = 0; k4 < 64; ++k4) {
    const float* wp = W2 + (size_t)(k4 * 4) * 256 + t;
    float w0 = wp[0], w1 = wp[256], w2 = wp[512], w3 = wp[768];
#pragma unroll
    for (int b = 0; b < 32; ++b) {
      float4 x4 = *(const float4*)(p1 + b * 256 + k4 * 4);
      acc[b] = fmaf(x4.x, w0, acc[b]); acc[b] = fmaf(x4.y, w1, acc[b]);
      acc[b] = fmaf(x4.z, w2, acc[b]); acc[b] = fmaf(x4.w, w3, acc[b]);
    }
  }
  for (int b = 0; b < 32; ++b) {
    float r = fmaxf(acc[b], 0.f);
    float u = rng_uniform(kd20, kd21, (unsigned)(b * 256 + t));
    pre2_all[(size_t)(s * 32 + b) * 256 + t] = (u < 0.5f) ? r * 2.f : 0.f;
  }
}

// ---------------------------------------------------------------------------
// k_escore: dp = s2 @ Wdec (exact R5 q-chunk + 64-half order) + conv + score.
// grid 256 = (b, lchunk p of 25 l's).
// ---------------------------------------------------------------------------
__global__ __launch_bounds__(256) void k_escore(const float* __restrict__ s2g,
                                                const float* __restrict__ Wdec,
                                                const float* __restrict__ encproj,
                                                const float* __restrict__ cwt,
                                                const float* __restrict__ cum,
                                                const float* __restrict__ Wself,
                                                float* __restrict__ sglob) {
  int b = blockIdx.x & 31, p = blockIdx.x >> 5;
  int t = threadIdx.x;
  __shared__ float s2l[1024];
  __shared__ float dp[128];
  __shared__ float ca[232];
  __shared__ float scpart[4];
  for (int i = t; i < 1024; i += 256) s2l[i] = s2g[b * 1024 + i];
  if (t < 232) ca[t] = (t >= 15 && t < 215) ? cum[b * 200 + (t - 15)] : 0.f;
  __syncthreads();
  if (t < 128) {
    // dp[a] = sum_{q=0..7} (a0_q + a1_q): identical order to R5's
    // cell2dp-partials (a0 = rows q*128..+64, a1 = rows q*128+64..+128)
    // followed by escore's ascending-q partial sum.
    float acc = 0.f;
    for (int q = 0; q < 8; ++q) {
      const float* wp = Wdec + (size_t)(q * 128) * 128 + t;
      float a0 = 0.f, a1 = 0.f;
#pragma unroll 8
      for (int r = 0; r < 64; ++r) a0 = fmaf(s2l[q * 128 + r], wp[(size_t)r * 128], a0);
#pragma unroll 8
      for (int r = 64; r < 128; ++r) a1 = fmaf(s2l[q * 128 + r], wp[(size_t)r * 128], a1);
      acc += a0 + a1;
    }
    dp[t] = acc;
  }
  __syncthreads();
  int a = t & 127, lh = t >> 7;
  float cwr[31];
#pragma unroll
  for (int k = 0; k < 31; ++k) cwr[k] = cwt[a * 32 + k];
  float wself = Wself[a];
  float dpr = dp[a];
  for (int ii = 0; ii < 13; ++ii) {
    int lo = ii * 2 + lh;
    int l = p * 25 + lo;
    float v = 0.f;
    if (lo < 25) {
      float conv = 0.f;
#pragma unroll
      for (int k = 0; k < 31; ++k) conv = fmaf(ca[l + k], cwr[k], conv);
      float e = tanhf(dpr + encproj[(size_t)(b * 200 + l) * 128 + a] + conv);
      v = e * wself;
    }
#pragma unroll
    for (int off = 32; off > 0; off >>= 1) v += __shfl_xor(v, off, 64);
    if ((t & 63) == 0) scpart[t >> 6] = v;
    __syncthreads();
    if (t == 0) sglob[b * 200 + p * 25 + ii * 2] = scpart[0] + scpart[1];
    if (t == 128 && ii < 12) sglob[b * 200 + p * 25 + ii * 2 + 1] = scpart[2] + scpart[3];
    __syncthreads();
  }
}

// ---------------------------------------------------------------------------
// k_attng: softmax (redundant/block) + g slices. grid 256 = (b, dchunk p).
// p==0 block also writes alpha to attn_out and updates cum.  [unchanged R5]
// ---------------------------------------------------------------------------
__global__ __launch_bounds__(256) void k_attng(const float* __restrict__ sglob,
                                               const float* __restrict__ e_out,
                                               float* __restrict__ cum,
                                               float* __restrict__ g_out,
                                               float* __restrict__ attn_out) {
  int b = blockIdx.x & 31, p = blockIdx.x >> 5;
  int t = threadIdx.x;
  __shared__ float sc[200];
  __shared__ float red[8];
  __shared__ float bcv[2];
  __shared__ float gpart[4][64];
  if (t < 200) sc[t] = sglob[b * 200 + t];
  __syncthreads();
  float v = (t < 200) ? sc[t] : -3.4e38f;
#pragma unroll
  for (int off = 32; off > 0; off >>= 1) v = fmaxf(v, __shfl_xor(v, off, 64));
  if ((t & 63) == 0) red[t >> 6] = v;
  __syncthreads();
  if (t == 0) bcv[0] = fmaxf(fmaxf(red[0], red[1]), fmaxf(red[2], red[3]));
  __syncthreads();
  float mx = bcv[0];
  float ex = (t < 200) ? expf(sc[t] - mx) : 0.f;
  float sv = ex;
#pragma unroll
  for (int off = 32; off > 0; off >>= 1) sv += __shfl_xor(sv, off, 64);
  if ((t & 63) == 0) red[4 + (t >> 6)] = sv;
  __syncthreads();
  if (t == 0) bcv[1] = (red[4] + red[5]) + (red[6] + red[7]);
  __syncthreads();
  float denom = bcv[1];
  if (t < 200) {
    float al = ex / denom;
    sc[t] = al;
    if (p == 0) {
      cum[b * 200 + t] += al;
      attn_out[(size_t)b * 100000 + t] = al;
    }
  }
  __syncthreads();
  int d = p * 64 + (t & 63), lq = t >> 6;
  const float* eb = e_out + (size_t)b * 102400 + d;
  float acc = 0.f;
  for (int l = lq * 50; l < lq * 50 + 50; ++l) acc = fmaf(sc[l], eb[(size_t)l * 512], acc);
  gpart[lq][t & 63] = acc;
  __syncthreads();
  if (t < 64)
    g_out[b * 512 + p * 64 + t] = (gpart[0][t] + gpart[1][t]) + (gpart[2][t] + gpart[3][t]);
}

// ---------------------------------------------------------------------------
// k_b1f: full-K LSTM1 GEMM + cell1. grid 256 (jt = 4-j tile), block 256.
// Thread (col = g*4+jj in 0..15, bq in 0..15) accumulates 2 batch rows for
// one gate-col across all 14 K-chunks (per-chunk partial from 0, added in
// cc order onto bias — exact R5 order). Cell phase is block-local via LDS.
// ---------------------------------------------------------------------------
__global__ __launch_bounds__(256) void k_b1f(
    const float* __restrict__ pre2_s, const float* __restrict__ s1old,
    const float* __restrict__ g_s,
    const float* __restrict__ Wys, const float* __restrict__ Wss, const float* __restrict__ Wgs,
    const float* __restrict__ bias, float* __restrict__ snew, float* __restrict__ cst,
    const unsigned* __restrict__ keyp) {
  __shared__ __align__(16) float xs[32 * 132];
  __shared__ float gl[32][16];
  int t = threadIdx.x, jt = blockIdx.x;
  int col = t & 15, bq = t >> 4;
  int g = col >> 2, jj = col & 3;
  int b0 = bq * 2, b1 = b0 + 1;
  int jcol = g * 1024 + jt * 4 + jj;
  float v0 = bias[jcol], v1 = v0;
  for (int cc = 0; cc < 14; ++cc) {
    __syncthreads();
    {
      int r = t >> 3, kq = t & 7;
      const float* src;
      if (cc < 2)       src = pre2_s + r * 256 + cc * 128;
      else if (cc < 10) src = s1old + r * 1024 + (cc - 2) * 128;
      else              src = g_s + r * 512 + (cc - 10) * 128;
      const float4* s4 = (const float4*)(src + kq * 16);
      float4* d4 = (float4*)(xs + r * 132 + kq * 16);
      d4[0] = s4[0]; d4[1] = s4[1]; d4[2] = s4[2]; d4[3] = s4[3];
    }
    __syncthreads();
    const float* W0; int k0;
    if (cc < 2)       { W0 = Wys; k0 = cc * 128; }
    else if (cc < 10) { W0 = Wss; k0 = (cc - 2) * 128; }
    else              { W0 = Wgs; k0 = (cc - 10) * 128; }
    const float* wp = W0 + (size_t)k0 * 4096 + jcol;
    const float4* x0 = (const float4*)(xs + b0 * 132);
    const float4* x1 = (const float4*)(xs + b1 * 132);
    float p0 = 0.f, p1 = 0.f;
#pragma unroll 8
    for (int k4 = 0; k4 < 32; ++k4) {
      float4 a0 = x0[k4], a1 = x1[k4];
      const float* wk = wp + (size_t)(k4 * 4) * 4096;
      float w0 = wk[0], w1 = wk[4096], w2 = wk[8192], w3 = wk[12288];
      p0 = fmaf(a0.x, w0, p0); p1 = fmaf(a1.x, w0, p1);
      p0 = fmaf(a0.y, w1, p0); p1 = fmaf(a1.y, w1, p1);
      p0 = fmaf(a0.z, w2, p0); p1 = fmaf(a1.z, w2, p1);
      p0 = fmaf(a0.w, w3, p0); p1 = fmaf(a1.w, w3, p1);
    }
    v0 += p0; v1 += p1;
  }
  gl[b0][col] = v0; gl[b1][col] = v1;
  __syncthreads();
  if (t < 128) {
    int b = t >> 2, j4 = t & 3;
    int j = jt * 4 + j4;
    int e = b * 1024 + j;
    float gi = gl[b][j4], gf = gl[b][4 + j4], gc = gl[b][8 + j4], go = gl[b][12 + j4];
    float u = rng_uniform(keyp[0], keyp[1], (unsigned)e);
    float m = floorf(u + 0.1f);
    float co = cst[e], so = s1old[e];
    float cn = fmaf(gatef(gf), co, gatef(gi) * tanhf(gc));
    float cnew = (m > 0.5f) ? co : cn;
    float sn = (m > 0.5f) ? so : (gatef(go) * tanhf(cnew));
    cst[e] = cnew;
    snew[e] = sn;
  }
}

// ---------------------------------------------------------------------------
// k_b2f: full-K LSTM2 GEMM (16 chunks) + cell2 -> s2 slot s+1. grid 256.
// ---------------------------------------------------------------------------
__global__ __launch_bounds__(256) void k_b2f(
    const float* __restrict__ s1new, const float* __restrict__ s2prev,
    const float* __restrict__ Wis, const float* __restrict__ Wss2,
    const float* __restrict__ bias, float* __restrict__ snew, float* __restrict__ cst,
    const unsigned* __restrict__ keyp) {
  __shared__ __align__(16) float xs[32 * 132];
  __shared__ float gl[32][16];
  int t = threadIdx.x, jt = blockIdx.x;
  int col = t & 15, bq = t >> 4;
  int g = col >> 2, jj = col & 3;
  int b0 = bq * 2, b1 = b0 + 1;
  int jcol = g * 1024 + jt * 4 + jj;
  float v0 = bias[jcol], v1 = v0;
  for (int cc = 0; cc < 16; ++cc) {
    __syncthreads();
    {
      int r = t >> 3, kq = t & 7;
      const float* src = (cc < 8) ? (s1new + r * 1024 + cc * 128)
                                  : (s2prev + r * 1024 + (cc - 8) * 128);
      const float4* s4 = (const float4*)(src + kq * 16);
      float4* d4 = (float4*)(xs + r * 132 + kq * 16);
      d4[0] = s4[0]; d4[1] = s4[1]; d4[2] = s4[2]; d4[3] = s4[3];
    }
    __syncthreads();
    const float* W0; int k0;
    if (cc < 8) { W0 = Wis;  k0 = cc * 128; }
    else        { W0 = Wss2; k0 = (cc - 8) * 128; }
    const float* wp = W0 + (size_t)k0 * 4096 + jcol;
    const float4* x0 = (const float4*)(xs + b0 * 132);
    const float4* x1 = (const float4*)(xs + b1 * 132);
    float p0 = 0.f, p1 = 0.f;
#pragma unroll 8
    for (int k4 = 0; k4 < 32; ++k4) {
      float4 a0 = x0[k4], a1 = x1[k4];
      const float* wk = wp + (size_t)(k4 * 4) * 4096;
      float w0 = wk[0], w1 = wk[4096], w2 = wk[8192], w3 = wk[12288];
      p0 = fmaf(a0.x, w0, p0); p1 = fmaf(a1.x, w0, p1);
      p0 = fmaf(a0.y, w1, p0); p1 = fmaf(a1.y, w1, p1);
      p0 = fmaf(a0.z, w2, p0); p1 = fmaf(a1.z, w2, p1);
      p0 = fmaf(a0.w, w3, p0); p1 = fmaf(a1.w, w3, p1);
    }
    v0 += p0; v1 += p1;
  }
  gl[b0][col] = v0; gl[b1][col] = v1;
  __syncthreads();
  if (t < 128) {
    int b = t >> 2, j4 = t & 3;
    int j = jt * 4 + j4;
    int e = b * 1024 + j;
    float gi = gl[b][j4], gf = gl[b][4 + j4], gc = gl[b][8 + j4], go = gl[b][12 + j4];
    float u = rng_uniform(keyp[0], keyp[1], (unsigned)e);
    float m = floorf(u + 0.1f);
    float co = cst[e], so = s2prev[e];
    float cn = fmaf(gatef(gf), co, gatef(gi) * tanhf(gc));
    float cnew = (m > 0.5f) ? co : cn;
    float sn = (m > 0.5f) ? so : (gatef(go) * tanhf(cnew));
    cst[e] = cnew;
    snew[e] = sn;
  }
}

// ---------------------------------------------------------------------------
// k_frame: deferred frame/token projection. grid 250.
// ---------------------------------------------------------------------------
__global__ __launch_bounds__(256) void k_frame(const float* __restrict__ s2_all,
                                               const float* __restrict__ g_all,
                                               const float* __restrict__ Wf,
                                               const float* __restrict__ bf,
                                               const float* __restrict__ Wt,
                                               const float* __restrict__ bt,
                                               float* __restrict__ out_frame,
                                               float* __restrict__ out_tok) {
  int s = blockIdx.x, t = threadIdx.x;
  __shared__ __align__(16) float xs[32 * 516];
  int b = t >> 3, ci = t & 7;
  int tb = t >> 1, tr = t & 1;
  float4 acc[5];
#pragma unroll
  for (int r = 0; r < 5; ++r) acc[r] = make_float4(0, 0, 0, 0);
  float tok = 0.f;
  for (int ch = 0; ch < 3; ++ch) {
    for (int i = 0; i < 64; ++i) {
      int idx = t + 256 * i;
      int rb = idx >> 9, kk = idx & 511;
      float vsrc = (ch < 2) ? s2_all[(size_t)(s + 1) * 32768 + rb * 1024 + ch * 512 + kk]
                            : g_all[(size_t)s * 16384 + rb * 512 + kk];
      xs[rb * 516 + kk] = vsrc;
    }
    __syncthreads();
    const float4* xv = (const float4*)xs;
    for (int k4 = 0; k4 < 128; ++k4) {
      float4 x4 = xv[b * 129 + k4];
      int kglob = ch * 512 + k4 * 4;
#pragma unroll
      for (int rep = 0; rep < 5; ++rep) {
        int c4 = ci * 4 + rep * 32;
        const float* wrow = Wf + (size_t)kglob * 160 + c4;
        float4 w0 = *(const float4*)(wrow);
        float4 w1 = *(const float4*)(wrow + 160);
        float4 w2 = *(const float4*)(wrow + 320);
        float4 w3 = *(const float4*)(wrow + 480);
        FMA4(acc[rep], x4.x, w0); FMA4(acc[rep], x4.y, w1);
        FMA4(acc[rep], x4.z, w2); FMA4(acc[rep], x4.w, w3);
      }
      if (t < 64) {
        float4 xt = xv[tb * 129 + k4];
        tok = fmaf(xt.x, Wt[(size_t)(kglob + 0) * 2 + tr], tok);
        tok = fmaf(xt.y, Wt[(size_t)(kglob + 1) * 2 + tr], tok);
        tok = fmaf(xt.z, Wt[(size_t)(kglob + 2) * 2 + tr], tok);
        tok = fmaf(xt.w, Wt[(size_t)(kglob + 3) * 2 + tr], tok);
      }
    }
    __syncthreads();
  }
#pragma unroll
  for (int rep = 0; rep < 5; ++rep) {
    float vals[4] = {acc[rep].x, acc[rep].y, acc[rep].z, acc[rep].w};
#pragma unroll
    for (int jj = 0; jj < 4; ++jj) {
      int cc = ci * 4 + rep * 32 + jj;
      float val = vals[jj] + bf[cc];
      int row = 2 * s + (cc >= 80 ? 1 : 0);
      int col = cc - (cc >= 80 ? 80 : 0);
      out_frame[(size_t)b * 40000 + (size_t)row * 80 + col] = val;
    }
  }
  if (t < 64) out_tok[(size_t)tb * 500 + 2 * s + tr] = tok + bt[tr];
}

// ---------------------------------------------------------------------------
extern "C" void kernel_launch(void* const* d_in, const int* in_sizes, int n_in,
                              void* d_out_v, int out_size, void* d_ws, size_t ws_size,
                              hipStream_t stream) {
  (void)in_sizes; (void)n_in; (void)out_size; (void)ws_size;
  const float* mel      = (const float*)d_in[0];
  const float* e_out    = (const float*)d_in[1];
  const float* conv_w   = (const float*)d_in[2];
  const float* Wcp      = (const float*)d_in[3];
  const float* Wenc     = (const float*)d_in[4];
  const float* benc     = (const float*)d_in[5];
  const float* Wdec     = (const float*)d_in[6];
  const float* Wself    = (const float*)d_in[7];
  const float* Wp1      = (const float*)d_in[8];
  const float* bp1      = (const float*)d_in[9];
  const float* Wp2      = (const float*)d_in[10];
  const float* bp2      = (const float*)d_in[11];
  const float* Wys      = (const float*)d_in[12];
  const float* Wss      = (const float*)d_in[13];
  const float* Wgs      = (const float*)d_in[14];
  const float* bgs      = (const float*)d_in[15];
  const float* Wis      = (const float*)d_in[16];
  const float* Wss2     = (const float*)d_in[17];
  const float* bss2     = (const float*)d_in[18];
  const float* Wf       = (const float*)d_in[19];
  const float* bf       = (const float*)d_in[20];
  const float* Wt       = (const float*)d_in[21];
  const float* bt       = (const float*)d_in[22];
  float* ws  = (float*)d_ws;
  float* out = (float*)d_out_v;
  const unsigned* keys = (const unsigned*)(ws + OFF_KEYS);

  hipLaunchKernelGGL(k_init, dim3(1024), dim3(256), 0, stream, ws, out, conv_w, Wcp);
  hipLaunchKernelGGL(k_encproj, dim3(200), dim3(256), 0, stream, e_out, Wenc, benc, ws + OFF_ENCPROJ);
  hipLaunchKernelGGL(k_prenet, dim3(250), dim3(256), 0, stream, mel, Wp1, bp1, Wp2, bp2, keys, ws + OFF_PRE2);

  for (int s = 0; s < NSTEP; ++s) {
    float* s1old = ws + OFF_S1 + (size_t)(s & 1) * 32768;
    float* s1new = ws + OFF_S1 + (size_t)((s + 1) & 1) * 32768;
    float* s2s   = ws + OFF_S2 + (size_t)s * 32768;
    float* s2n   = ws + OFF_S2 + (size_t)(s + 1) * 32768;
    float* gs    = ws + OFF_G  + (size_t)s * 16384;
    hipLaunchKernelGGL(k_escore, dim3(256), dim3(256), 0, stream,
                       s2s, Wdec, ws + OFF_ENCPROJ, ws + OFF_CWT, ws + OFF_CUM,
                       Wself, ws + OFF_SC);
    hipLaunchKernelGGL(k_attng, dim3(256), dim3(256), 0, stream,
                       ws + OFF_SC, e_out, ws + OFF_CUM, gs,
                       out + OUT_ATTN + (size_t)s * 200);
    hipLaunchKernelGGL(k_b1f, dim3(256), dim3(256), 0, stream,
                       ws + OFF_PRE2 + (size_t)s * 8192, s1old, gs, Wys, Wss, Wgs,
                       bgs, s1new, ws + OFF_C1, keys + s * 8 + 4);
    hipLaunchKernelGGL(k_b2f, dim3(256), dim3(256), 0, stream,
                       s1new, s2s, Wis, Wss2,
                       bss2, s2n, ws + OFF_C2, keys + s * 8 + 6);
  }
  hipLaunchKernelGGL(k_frame, dim3(250), dim3(256), 0, stream,
                     ws + OFF_S2, ws + OFF_G, Wf, bf, Wt, bt, out, out + OUT_TOK);
}

// Round 5
// 24473.376 us; speedup vs baseline: 4.3201x; 2.4083x over previous
//
#include <hip/hip_runtime.h>
#include <cstdint>
#include <cstddef>

// ---------------------------------------------------------------------------
// Tacotron2 decoder, MI355X. Round 9: R5 structure (15.5 ms verified) with
// cell2dp absorbed into escore (6 -> 5 kernels/step). escore block (b,p)
// computes the LSTM2 cell of step s-1 for ALL 1024 j of batch b (8x redundant
// across p-blocks; identical values -> benign duplicate writes), keeps s2 in
// LDS for the dp GEMM (R8-verified bit-exact), then conv+tanh+score as R5.
// c2 ping-pongs between OFF_C2 / OFF_C2B to avoid the RMW race. k_cellfin
// (one launch, after loop) produces s2 slot 250 for k_frame.
// R8 lesson encoded: never drop below ~2 waves/SIMD; no serial full-K blocks.
// ---------------------------------------------------------------------------

static constexpr int NSTEP = 250;

// workspace offsets (floats). total = 19,322,880 floats (~77.3 MB)
static constexpr size_t OFF_ENCPROJ = 0;               // 819200
static constexpr size_t OFF_CWT     = 819200;          // 4096
static constexpr size_t OFF_KEYS    = 823296;          // 2048 (250*8 uints)
static constexpr size_t OFF_PRE2    = 825344;          // 2048000
static constexpr size_t OFF_G       = 2873344;         // 4096000
static constexpr size_t OFF_S2      = 6969344;         // 251*32768 = 8224768
static constexpr size_t OFF_S1      = 15194112;        // 65536 (ping-pong)
static constexpr size_t OFF_C1      = 15259648;        // 32768
static constexpr size_t OFF_C2     = 15292416;         // 32768 (c2 buf 0)
static constexpr size_t OFF_CUM     = 15325184;        // 8192 (6400 used)
static constexpr size_t OFF_C2B     = 15333376;        // 32768 (c2 buf 1, ex-dpart)
static constexpr size_t OFF_SC      = 15366144;        // 8192 (6400 used)
static constexpr size_t OFF_P1      = 15390720;        // 14*32*4096 = 1835008
static constexpr size_t OFF_P2      = 17225728;        // 16*32*4096 = 2097152

// d_out offsets (floats)
static constexpr size_t OUT_TOK  = 1280000;
static constexpr size_t OUT_ATTN = 1296000;

// ---------------------------------------------------------------------------
// Threefry-2x32 (JAX partitionable split — verified bit-exact)
// ---------------------------------------------------------------------------
__device__ __forceinline__ uint2 threefry(unsigned k0, unsigned k1, unsigned c0, unsigned c1) {
  unsigned ks2 = k0 ^ k1 ^ 0x1BD11BDAu;
  unsigned x0 = c0 + k0, x1 = c1 + k1;
#define TFR(rot) { x0 += x1; x1 = (x1 << (rot)) | (x1 >> (32 - (rot))); x1 ^= x0; }
  TFR(13) TFR(15) TFR(26) TFR(6)   x0 += k1;  x1 += ks2 + 1u;
  TFR(17) TFR(29) TFR(16) TFR(24)  x0 += ks2; x1 += k0 + 2u;
  TFR(13) TFR(15) TFR(26) TFR(6)   x0 += k0;  x1 += k1 + 3u;
  TFR(17) TFR(29) TFR(16) TFR(24)  x0 += k1;  x1 += ks2 + 4u;
  TFR(13) TFR(15) TFR(26) TFR(6)   x0 += ks2; x1 += k0 + 5u;
#undef TFR
  return make_uint2(x0, x1);
}

__device__ __forceinline__ float u32_to_uniform(unsigned b) {
  return __uint_as_float((b >> 9) | 0x3f800000u) - 1.0f;
}

__device__ __forceinline__ float rng_uniform(unsigned k0, unsigned k1, unsigned i) {
  uint2 h = threefry(k0, k1, 0u, i);
  return u32_to_uniform(h.x ^ h.y);
}

__device__ __forceinline__ float gatef(float x) { return tanhf(x * 0.5f) * 0.5f + 0.5f; }

#define FMA4(A, S, W) { (A).x = fmaf((S), (W).x, (A).x); (A).y = fmaf((S), (W).y, (A).y); \
                        (A).z = fmaf((S), (W).z, (A).z); (A).w = fmaf((S), (W).w, (A).w); }

// ---------------------------------------------------------------------------
// k_init: zero states (s1 x2, c1, c2 both bufs, cum) + s2 slot 0, attn rows
// 250..499, RNG keys, CWt precompute.
// ---------------------------------------------------------------------------
__global__ __launch_bounds__(256) void k_init(float* __restrict__ ws, float* __restrict__ out,
                                              const float* __restrict__ conv_w,
                                              const float* __restrict__ Wcp) {
  const size_t NZERO1 = 172032;   // s1(2x)+c1+c2+cum+c2b contiguous at OFF_S1
  const size_t NZERO2 = 32768;    // s2_all slot 0
  const size_t NATTN  = 1600000;  // attn rows 250..499
  const size_t NKEYS  = 250;
  const size_t NCWT   = 4096;
  const size_t TOTAL  = NZERO1 + NZERO2 + NATTN + NKEYS + NCWT;
  unsigned* keys = (unsigned*)(ws + OFF_KEYS);
  for (size_t i = (size_t)blockIdx.x * 256 + threadIdx.x; i < TOTAL; i += (size_t)gridDim.x * 256) {
    if (i < NZERO1) {
      ws[OFF_S1 + i] = 0.f;
    } else if (i < NZERO1 + NZERO2) {
      ws[OFF_S2 + (i - NZERO1)] = 0.f;
    } else if (i < NZERO1 + NZERO2 + NATTN) {
      size_t r = i - NZERO1 - NZERO2;
      size_t b = r / 50000, rem = r % 50000;
      out[OUT_ATTN + b * 100000 + 50000 + rem] = 0.f;
    } else if (i < NZERO1 + NZERO2 + NATTN + NKEYS) {
      int s = (int)(i - NZERO1 - NZERO2 - NATTN);
      uint2 F = threefry(0u, 1234u, 0u, (unsigned)s);
      uint2 kd1 = threefry(F.x, F.y, 0u, 0u);
      uint2 kd2 = threefry(F.x, F.y, 0u, 1u);
      uint2 kz1 = threefry(F.x, F.y, 0u, 2u);
      uint2 kz2 = threefry(F.x, F.y, 0u, 3u);
      keys[s * 8 + 0] = kd1.x; keys[s * 8 + 1] = kd1.y;
      keys[s * 8 + 2] = kd2.x; keys[s * 8 + 3] = kd2.y;
      keys[s * 8 + 4] = kz1.x; keys[s * 8 + 5] = kz1.y;
      keys[s * 8 + 6] = kz2.x; keys[s * 8 + 7] = kz2.y;
    } else {
      size_t r = i - NZERO1 - NZERO2 - NATTN - NKEYS;   // [0,4096)
      int a = (int)(r >> 5), kk = (int)(r & 31);
      float v = 0.f;
      if (kk < 31) {
        for (int f = 0; f < 32; ++f) v = fmaf(conv_w[f * 31 + kk], Wcp[f * 128 + a], v);
      }
      ws[OFF_CWT + r] = v;   // CWt[a][k], row stride 32
    }
  }
}

// ---------------------------------------------------------------------------
// k_encproj: encproj = e_outputs @ W_encproj + b  ([6400,512]@[512,128])
// ---------------------------------------------------------------------------
__global__ __launch_bounds__(256) void k_encproj(const float* __restrict__ e_out,
                                                 const float* __restrict__ Wenc,
                                                 const float* __restrict__ benc,
                                                 float* __restrict__ encproj) {
  __shared__ __align__(16) float xs[32 * 516];
  int t = threadIdx.x;
  int r0 = blockIdx.x * 32;
  for (int i = 0; i < 64; ++i) {
    int idx = t + 256 * i; int rb = idx >> 9, kk = idx & 511;
    xs[rb * 516 + kk] = e_out[(size_t)(r0 + rb) * 512 + kk];
  }
  __syncthreads();
  int a = t & 127, rh = t >> 7;
  float acc[16];
#pragma unroll
  for (int r = 0; r < 16; ++r) acc[r] = 0.f;
  const float4* xv = (const float4*)xs;
  for (int k4 = 0; k4 < 128; ++k4) {
    const float* wp = Wenc + (size_t)(k4 * 4) * 128 + a;
    float w0 = wp[0], w1 = wp[128], w2 = wp[256], w3 = wp[384];
#pragma unroll
    for (int r = 0; r < 16; ++r) {
      float4 x4 = xv[(rh * 16 + r) * 129 + k4];
      acc[r] = fmaf(x4.x, w0, acc[r]); acc[r] = fmaf(x4.y, w1, acc[r]);
      acc[r] = fmaf(x4.z, w2, acc[r]); acc[r] = fmaf(x4.w, w3, acc[r]);
    }
  }
  float bb = benc[a];
  for (int r = 0; r < 16; ++r)
    encproj[(size_t)(r0 + rh * 16 + r) * 128 + a] = acc[r] + bb;
}

// ---------------------------------------------------------------------------
// k_prenet: all 250 steps, exact dropout
// ---------------------------------------------------------------------------
__global__ __launch_bounds__(256) void k_prenet(const float* __restrict__ mel,
                                                const float* __restrict__ W1, const float* __restrict__ b1,
                                                const float* __restrict__ W2, const float* __restrict__ b2,
                                                const unsigned* __restrict__ keys,
                                                float* __restrict__ pre2_all) {
  int s = blockIdx.x, t = threadIdx.x;
  __shared__ __align__(16) float prev[32 * 80];
  __shared__ __align__(16) float p1[32 * 256];
  for (int i = 0; i < 10; ++i) {
    int idx = t + 256 * i;
    int bb = idx / 80, vv = idx % 80;
    prev[idx] = (s == 0) ? 0.f : mel[(size_t)bb * 40000 + (size_t)(2 * s - 1) * 80 + vv];
  }
  __syncthreads();
  unsigned kd10 = keys[s * 8 + 0], kd11 = keys[s * 8 + 1];
  unsigned kd20 = keys[s * 8 + 2], kd21 = keys[s * 8 + 3];
  float acc[32];
  float bias = b1[t];
#pragma unroll
  for (int b = 0; b < 32; ++b) acc[b] = bias;
  for (int k4 = 0; k4 < 20; ++k4) {
    const float* wp = W1 + (size_t)(k4 * 4) * 256 + t;
    float w0 = wp[0], w1 = wp[256], w2 = wp[512], w3 = wp[768];
#pragma unroll
    for (int b = 0; b < 32; ++b) {
      float4 x4 = *(const float4*)(prev + b * 80 + k4 * 4);
      acc[b] = fmaf(x4.x, w0, acc[b]); acc[b] = fmaf(x4.y, w1, acc[b]);
      acc[b] = fmaf(x4.z, w2, acc[b]); acc[b] = fmaf(x4.w, w3, acc[b]);
    }
  }
#pragma unroll
  for (int b = 0; b < 32; ++b) {
    float r = fmaxf(acc[b], 0.f);
    float u = rng_uniform(kd10, kd11, (unsigned)(b * 256 + t));
    p1[b * 256 + t] = (u < 0.5f) ? r * 2.f : 0.f;
  }
  __syncthreads();
  float bias2 = b2[t];
#pragma unroll
  for (int b = 0; b < 32; ++b) acc[b] = bias2;
  for (int k4 = 0; k4 < 64; ++k4) {
    const float* wp = W2 + (size_t)(k4 * 4) * 256 + t;
    float w0 = wp[0], w1 = wp[256], w2 = wp[512], w3 = wp[768];
#pragma unroll
    for (int b = 0; b < 32; ++b) {
      float4 x4 = *(const float4*)(p1 + b * 256 + k4 * 4);
      acc[b] = fmaf(x4.x, w0, acc[b]); acc[b] = fmaf(x4.y, w1, acc[b]);
      acc[b] = fmaf(x4.z, w2, acc[b]); acc[b] = fmaf(x4.w, w3, acc[b]);
    }
  }
  for (int b = 0; b < 32; ++b) {
    float r = fmaxf(acc[b], 0.f);
    float u = rng_uniform(kd20, kd21, (unsigned)(b * 256 + t));
    pre2_all[(size_t)(s * 32 + b) * 256 + t] = (u < 0.5f) ? r * 2.f : 0.f;
  }
}

// ---------------------------------------------------------------------------
// k_escore2: fused cell2(s-1) + dp + conv + score. grid 256 = (b, p).
// Cell phase: all 1024 j of batch b, 8x redundant across p (identical values,
// benign dup writes; c2 ping-pong avoids RMW race). dp/conv/score: exact
// R5/R8 reduction orders.
// ---------------------------------------------------------------------------
__global__ __launch_bounds__(256) void k_escore2(
    int s,
    const float* __restrict__ part,      // P2 (written at step s-1)
    const float* __restrict__ bias2,     // bss2
    const float* __restrict__ s2old,     // slot s-1
    float* __restrict__ s2new,           // slot s (pre-zeroed when s==0)
    const float* __restrict__ c2old,
    float* __restrict__ c2new,
    const unsigned* __restrict__ keys,
    const float* __restrict__ Wdec,
    const float* __restrict__ encproj,
    const float* __restrict__ cwt,
    const float* __restrict__ cum,
    const float* __restrict__ Wself,
    float* __restrict__ sglob) {
  int b = blockIdx.x & 31, p = blockIdx.x >> 5;
  int t = threadIdx.x;
  __shared__ float s2l[1024];
  __shared__ float dp[128];
  __shared__ float ca[232];
  __shared__ float scpart[4];
  // ---- phase A: LSTM2 cell of step s-1 (redundant per p; bit-exact dup) ----
  if (s > 0) {
    const unsigned* keyp = keys + (size_t)(s - 1) * 8 + 6;
    unsigned kk0 = keyp[0], kk1 = keyp[1];
    for (int i = t; i < 1024; i += 256) {
      int e = b * 1024 + i;
      float gi = bias2[i], gf = bias2[1024 + i], gc = bias2[2048 + i], go = bias2[3072 + i];
      const float* pc = part + (size_t)b * 4096 + i;
#pragma unroll
      for (int cc = 0; cc < 16; ++cc) {
        const float* p2 = pc + (size_t)cc * 131072;
        gi += p2[0]; gf += p2[1024]; gc += p2[2048]; go += p2[3072];
      }
      float u = rng_uniform(kk0, kk1, (unsigned)e);
      float m = floorf(u + 0.1f);
      float co = c2old[e], so = s2old[e];
      float cn = fmaf(gatef(gf), co, gatef(gi) * tanhf(gc));
      float cnew = (m > 0.5f) ? co : cn;
      float sn = (m > 0.5f) ? so : (gatef(go) * tanhf(cnew));
      c2new[e] = cnew;
      s2new[e] = sn;
      s2l[i] = sn;
    }
  } else {
    for (int i = t; i < 1024; i += 256) s2l[i] = 0.f;
  }
  if (t < 232) ca[t] = (t >= 15 && t < 215) ? cum[b * 200 + (t - 15)] : 0.f;
  __syncthreads();
  // ---- phase B: dp = s2 @ Wdec (exact R5 q-chunk + 64-half order) ----
  if (t < 128) {
    float acc = 0.f;
    for (int q = 0; q < 8; ++q) {
      const float* wp = Wdec + (size_t)(q * 128) * 128 + t;
      float a0 = 0.f, a1 = 0.f;
#pragma unroll 8
      for (int r = 0; r < 64; ++r) a0 = fmaf(s2l[q * 128 + r], wp[(size_t)r * 128], a0);
#pragma unroll 8
      for (int r = 64; r < 128; ++r) a1 = fmaf(s2l[q * 128 + r], wp[(size_t)r * 128], a1);
      acc += a0 + a1;
    }
    dp[t] = acc;
  }
  __syncthreads();
  // ---- phase C: conv + tanh + score (exact R5 order) ----
  int a = t & 127, lh = t >> 7;
  float cwr[31];
#pragma unroll
  for (int k = 0; k < 31; ++k) cwr[k] = cwt[a * 32 + k];
  float wself = Wself[a];
  float dpr = dp[a];
  for (int ii = 0; ii < 13; ++ii) {
    int lo = ii * 2 + lh;
    int l = p * 25 + lo;
    float v = 0.f;
    if (lo < 25) {
      float conv = 0.f;
#pragma unroll
      for (int k = 0; k < 31; ++k) conv = fmaf(ca[l + k], cwr[k], conv);
      float e = tanhf(dpr + encproj[(size_t)(b * 200 + l) * 128 + a] + conv);
      v = e * wself;
    }
#pragma unroll
    for (int off = 32; off > 0; off >>= 1) v += __shfl_xor(v, off, 64);
    if ((t & 63) == 0) scpart[t >> 6] = v;
    __syncthreads();
    if (t == 0) sglob[b * 200 + p * 25 + ii * 2] = scpart[0] + scpart[1];
    if (t == 128 && ii < 12) sglob[b * 200 + p * 25 + ii * 2 + 1] = scpart[2] + scpart[3];
    __syncthreads();
  }
}

// ---------------------------------------------------------------------------
// k_attng: softmax (redundant/block) + g slices. grid 256 = (b, dchunk p).
// p==0 block also writes alpha to attn_out and updates cum.  [unchanged R5]
// ---------------------------------------------------------------------------
__global__ __launch_bounds__(256) void k_attng(const float* __restrict__ sglob,
                                               const float* __restrict__ e_out,
                                               float* __restrict__ cum,
                                               float* __restrict__ g_out,
                                               float* __restrict__ attn_out) {
  int b = blockIdx.x & 31, p = blockIdx.x >> 5;
  int t = threadIdx.x;
  __shared__ float sc[200];
  __shared__ float red[8];
  __shared__ float bcv[2];
  __shared__ float gpart[4][64];
  if (t < 200) sc[t] = sglob[b * 200 + t];
  __syncthreads();
  float v = (t < 200) ? sc[t] : -3.4e38f;
#pragma unroll
  for (int off = 32; off > 0; off >>= 1) v = fmaxf(v, __shfl_xor(v, off, 64));
  if ((t & 63) == 0) red[t >> 6] = v;
  __syncthreads();
  if (t == 0) bcv[0] = fmaxf(fmaxf(red[0], red[1]), fmaxf(red[2], red[3]));
  __syncthreads();
  float mx = bcv[0];
  float ex = (t < 200) ? expf(sc[t] - mx) : 0.f;
  float sv = ex;
#pragma unroll
  for (int off = 32; off > 0; off >>= 1) sv += __shfl_xor(sv, off, 64);
  if ((t & 63) == 0) red[4 + (t >> 6)] = sv;
  __syncthreads();
  if (t == 0) bcv[1] = (red[4] + red[5]) + (red[6] + red[7]);
  __syncthreads();
  float denom = bcv[1];
  if (t < 200) {
    float al = ex / denom;
    sc[t] = al;
    if (p == 0) {
      cum[b * 200 + t] += al;
      attn_out[(size_t)b * 100000 + t] = al;
    }
  }
  __syncthreads();
  int d = p * 64 + (t & 63), lq = t >> 6;
  const float* eb = e_out + (size_t)b * 102400 + d;
  float acc = 0.f;
  for (int l = lq * 50; l < lq * 50 + 50; ++l) acc = fmaf(sc[l], eb[(size_t)l * 512], acc);
  gpart[lq][t & 63] = acc;
  __syncthreads();
  if (t < 64)
    g_out[b * 512 + p * 64 + t] = (gpart[0][t] + gpart[1][t]) + (gpart[2][t] + gpart[3][t]);
}

// ---------------------------------------------------------------------------
// LSTM GEMM partials only. Block = (coltile jt: gate-quad cols, K-chunk c).
// [unchanged R5]
// ---------------------------------------------------------------------------
__device__ __forceinline__ void gemm_body(
    const float* __restrict__ W0, int k0,
    float* __restrict__ part, int c, int jt,
    const float* __restrict__ xs /*staged 32x132*/) {
  int t = threadIdx.x;
  int jq = t & 31, bq = t >> 5;
  int j = jt * 32 + jq;
  float4 acc[4];
  acc[0] = acc[1] = acc[2] = acc[3] = make_float4(0, 0, 0, 0);
  const float4* xv = (const float4*)xs;
  const float* Wb = W0 + (size_t)k0 * 4096 + j;
#pragma unroll 4
  for (int k4 = 0; k4 < 32; ++k4) {
    float4 xq[4];
    xq[0] = xv[(bq * 4 + 0) * 33 + k4];
    xq[1] = xv[(bq * 4 + 1) * 33 + k4];
    xq[2] = xv[(bq * 4 + 2) * 33 + k4];
    xq[3] = xv[(bq * 4 + 3) * 33 + k4];
    const float* wr = Wb + (size_t)(k4 * 4) * 4096;
#pragma unroll
    for (int ks = 0; ks < 4; ++ks) {
      float wi = wr[0], wf = wr[1024], wc = wr[2048], wo = wr[3072];
      wr += 4096;
#pragma unroll
      for (int r = 0; r < 4; ++r) {
        float xval = ((const float*)&xq[r])[ks];
        acc[r].x = fmaf(xval, wi, acc[r].x);
        acc[r].y = fmaf(xval, wf, acc[r].y);
        acc[r].z = fmaf(xval, wc, acc[r].z);
        acc[r].w = fmaf(xval, wo, acc[r].w);
      }
    }
  }
  float* pb = part + (size_t)c * 131072 + (size_t)(bq * 4) * 4096 + j;
#pragma unroll
  for (int r = 0; r < 4; ++r) {
    float* pr = pb + r * 4096;
    pr[0] = acc[r].x; pr[1024] = acc[r].y; pr[2048] = acc[r].z; pr[3072] = acc[r].w;
  }
}

// LSTM1 GEMM: x = [pre2(256) | s1old(1024) | g(512)], 14 chunks. grid 448.
__global__ __launch_bounds__(256) void k_b1g(
    const float* __restrict__ pre2_s, const float* __restrict__ s1old,
    const float* __restrict__ g_s,
    const float* __restrict__ Wys, const float* __restrict__ Wss, const float* __restrict__ Wgs,
    float* __restrict__ part) {
  int t = threadIdx.x;
  int jt = blockIdx.x & 31, c = blockIdx.x >> 5;   // c in 0..13
  __shared__ __align__(16) float xs[32 * 132];
  {
    int r = t >> 3, kq = t & 7;
    const float* src;
    if (c < 2)       src = pre2_s + r * 256 + c * 128;
    else if (c < 10) src = s1old + r * 1024 + (c - 2) * 128;
    else             src = g_s + r * 512 + (c - 10) * 128;
    const float4* s4 = (const float4*)(src + kq * 16);
    float4* d4 = (float4*)(xs + r * 132 + kq * 16);
    d4[0] = s4[0]; d4[1] = s4[1]; d4[2] = s4[2]; d4[3] = s4[3];
  }
  const float* W0; int k0;
  if (c < 2)       { W0 = Wys; k0 = c * 128; }
  else if (c < 10) { W0 = Wss; k0 = (c - 2) * 128; }
  else             { W0 = Wgs; k0 = (c - 10) * 128; }
  __syncthreads();
  gemm_body(W0, k0, part, c, jt, xs);
}

// LSTM2 GEMM: x = [s1new(1024) | s2prev(1024)], 16 chunks. grid 512.
__global__ __launch_bounds__(256) void k_b2g(
    const float* __restrict__ s1new, const float* __restrict__ s2prev,
    const float* __restrict__ Wis, const float* __restrict__ Wss2,
    float* __restrict__ part) {
  int t = threadIdx.x;
  int jt = blockIdx.x & 31, c = blockIdx.x >> 5;   // c in 0..15
  __shared__ __align__(16) float xs[32 * 132];
  {
    int r = t >> 3, kq = t & 7;
    const float* src = (c < 8) ? (s1new + r * 1024 + c * 128)
                               : (s2prev + r * 1024 + (c - 8) * 128);
    const float4* s4 = (const float4*)(src + kq * 16);
    float4* d4 = (float4*)(xs + r * 132 + kq * 16);
    d4[0] = s4[0]; d4[1] = s4[1]; d4[2] = s4[2]; d4[3] = s4[3];
  }
  const float* W0; int k0;
  if (c < 8) { W0 = Wis;  k0 = c * 128; }
  else       { W0 = Wss2; k0 = (c - 8) * 128; }
  __syncthreads();
  gemm_body(W0, k0, part, c, jt, xs);
}

// ---------------------------------------------------------------------------
// k_cell1: reduce 14 partial chunks + bias + gates + zoneout for LSTM1.
// grid 128 x 256 = one thread per (b,j) element.   [unchanged R5]
// ---------------------------------------------------------------------------
__global__ __launch_bounds__(256) void k_cell1(
    const float* __restrict__ part, const float* __restrict__ bias,
    const float* __restrict__ sold, float* __restrict__ snew, float* __restrict__ cst,
    const unsigned* __restrict__ keyp) {
  int e = blockIdx.x * 256 + threadIdx.x;   // [0, 32768)
  int b = e >> 10, j = e & 1023;
  float gi = bias[j], gf = bias[1024 + j], gc = bias[2048 + j], go = bias[3072 + j];
  const float* pc = part + (size_t)b * 4096 + j;
#pragma unroll
  for (int cc = 0; cc < 14; ++cc) {
    const float* p2 = pc + (size_t)cc * 131072;
    gi += p2[0]; gf += p2[1024]; gc += p2[2048]; go += p2[3072];
  }
  float u = rng_uniform(keyp[0], keyp[1], (unsigned)e);
  float m = floorf(u + 0.1f);
  float co = cst[e], so = sold[e];
  float cn = fmaf(gatef(gf), co, gatef(gi) * tanhf(gc));
  float cnew = (m > 0.5f) ? co : cn;
  float sn = (m > 0.5f) ? so : (gatef(go) * tanhf(cnew));
  cst[e] = cnew;
  snew[e] = sn;
}

// ---------------------------------------------------------------------------
// k_cellfin: LSTM2 cell of step 249 -> s2 slot 250 (for k_frame). grid 128.
// Split c2 read/write pointers (ping-pong).
// ---------------------------------------------------------------------------
__global__ __launch_bounds__(256) void k_cellfin(
    const float* __restrict__ part, const float* __restrict__ bias,
    const float* __restrict__ sold, float* __restrict__ snew,
    const float* __restrict__ c2old, float* __restrict__ c2new,
    const unsigned* __restrict__ keyp) {
  int e = blockIdx.x * 256 + threadIdx.x;   // [0, 32768)
  int b = e >> 10, j = e & 1023;
  float gi = bias[j], gf = bias[1024 + j], gc = bias[2048 + j], go = bias[3072 + j];
  const float* pc = part + (size_t)b * 4096 + j;
#pragma unroll
  for (int cc = 0; cc < 16; ++cc) {
    const float* p2 = pc + (size_t)cc * 131072;
    gi += p2[0]; gf += p2[1024]; gc += p2[2048]; go += p2[3072];
  }
  float u = rng_uniform(keyp[0], keyp[1], (unsigned)e);
  float m = floorf(u + 0.1f);
  float co = c2old[e], so = sold[e];
  float cn = fmaf(gatef(gf), co, gatef(gi) * tanhf(gc));
  float cnew = (m > 0.5f) ? co : cn;
  float sn = (m > 0.5f) ? so : (gatef(go) * tanhf(cnew));
  c2new[e] = cnew;
  snew[e] = sn;
}

// ---------------------------------------------------------------------------
// k_frame: deferred frame/token projection. grid 250.   [unchanged R5]
// ---------------------------------------------------------------------------
__global__ __launch_bounds__(256) void k_frame(const float* __restrict__ s2_all,
                                               const float* __restrict__ g_all,
                                               const float* __restrict__ Wf,
                                               const float* __restrict__ bf,
                                               const float* __restrict__ Wt,
                                               const float* __restrict__ bt,
                                               float* __restrict__ out_frame,
                                               float* __restrict__ out_tok) {
  int s = blockIdx.x, t = threadIdx.x;
  __shared__ __align__(16) float xs[32 * 516];
  int b = t >> 3, ci = t & 7;
  int tb = t >> 1, tr = t & 1;
  float4 acc[5];
#pragma unroll
  for (int r = 0; r < 5; ++r) acc[r] = make_float4(0, 0, 0, 0);
  float tok = 0.f;
  for (int ch = 0; ch < 3; ++ch) {
    for (int i = 0; i < 64; ++i) {
      int idx = t + 256 * i;
      int rb = idx >> 9, kk = idx & 511;
      float vsrc = (ch < 2) ? s2_all[(size_t)(s + 1) * 32768 + rb * 1024 + ch * 512 + kk]
                            : g_all[(size_t)s * 16384 + rb * 512 + kk];
      xs[rb * 516 + kk] = vsrc;
    }
    __syncthreads();
    const float4* xv = (const float4*)xs;
    for (int k4 = 0; k4 < 128; ++k4) {
      float4 x4 = xv[b * 129 + k4];
      int kglob = ch * 512 + k4 * 4;
#pragma unroll
      for (int rep = 0; rep < 5; ++rep) {
        int c4 = ci * 4 + rep * 32;
        const float* wrow = Wf + (size_t)kglob * 160 + c4;
        float4 w0 = *(const float4*)(wrow);
        float4 w1 = *(const float4*)(wrow + 160);
        float4 w2 = *(const float4*)(wrow + 320);
        float4 w3 = *(const float4*)(wrow + 480);
        FMA4(acc[rep], x4.x, w0); FMA4(acc[rep], x4.y, w1);
        FMA4(acc[rep], x4.z, w2); FMA4(acc[rep], x4.w, w3);
      }
      if (t < 64) {
        float4 xt = xv[tb * 129 + k4];
        tok = fmaf(xt.x, Wt[(size_t)(kglob + 0) * 2 + tr], tok);
        tok = fmaf(xt.y, Wt[(size_t)(kglob + 1) * 2 + tr], tok);
        tok = fmaf(xt.z, Wt[(size_t)(kglob + 2) * 2 + tr], tok);
        tok = fmaf(xt.w, Wt[(size_t)(kglob + 3) * 2 + tr], tok);
      }
    }
    __syncthreads();
  }
#pragma unroll
  for (int rep = 0; rep < 5; ++rep) {
    float vals[4] = {acc[rep].x, acc[rep].y, acc[rep].z, acc[rep].w};
#pragma unroll
    for (int jj = 0; jj < 4; ++jj) {
      int cc = ci * 4 + rep * 32 + jj;
      float val = vals[jj] + bf[cc];
      int row = 2 * s + (cc >= 80 ? 1 : 0);
      int col = cc - (cc >= 80 ? 80 : 0);
      out_frame[(size_t)b * 40000 + (size_t)row * 80 + col] = val;
    }
  }
  if (t < 64) out_tok[(size_t)tb * 500 + 2 * s + tr] = tok + bt[tr];
}

// ---------------------------------------------------------------------------
extern "C" void kernel_launch(void* const* d_in, const int* in_sizes, int n_in,
                              void* d_out_v, int out_size, void* d_ws, size_t ws_size,
                              hipStream_t stream) {
  (void)in_sizes; (void)n_in; (void)out_size; (void)ws_size;
  const float* mel      = (const float*)d_in[0];
  const float* e_out    = (const float*)d_in[1];
  const float* conv_w   = (const float*)d_in[2];
  const float* Wcp      = (const float*)d_in[3];
  const float* Wenc     = (const float*)d_in[4];
  const float* benc     = (const float*)d_in[5];
  const float* Wdec     = (const float*)d_in[6];
  const float* Wself    = (const float*)d_in[7];
  const float* Wp1      = (const float*)d_in[8];
  const float* bp1      = (const float*)d_in[9];
  const float* Wp2      = (const float*)d_in[10];
  const float* bp2      = (const float*)d_in[11];
  const float* Wys      = (const float*)d_in[12];
  const float* Wss      = (const float*)d_in[13];
  const float* Wgs      = (const float*)d_in[14];
  const float* bgs      = (const float*)d_in[15];
  const float* Wis      = (const float*)d_in[16];
  const float* Wss2     = (const float*)d_in[17];
  const float* bss2     = (const float*)d_in[18];
  const float* Wf       = (const float*)d_in[19];
  const float* bf       = (const float*)d_in[20];
  const float* Wt       = (const float*)d_in[21];
  const float* bt       = (const float*)d_in[22];
  float* ws  = (float*)d_ws;
  float* out = (float*)d_out_v;
  const unsigned* keys = (const unsigned*)(ws + OFF_KEYS);

  hipLaunchKernelGGL(k_init, dim3(1024), dim3(256), 0, stream, ws, out, conv_w, Wcp);
  hipLaunchKernelGGL(k_encproj, dim3(200), dim3(256), 0, stream, e_out, Wenc, benc, ws + OFF_ENCPROJ);
  hipLaunchKernelGGL(k_prenet, dim3(250), dim3(256), 0, stream, mel, Wp1, bp1, Wp2, bp2, keys, ws + OFF_PRE2);

  for (int s = 0; s < NSTEP; ++s) {
    float* s1old = ws + OFF_S1 + (size_t)(s & 1) * 32768;
    float* s1new = ws + OFF_S1 + (size_t)((s + 1) & 1) * 32768;
    float* s2old = ws + OFF_S2 + (size_t)(s > 0 ? s - 1 : 0) * 32768;
    float* s2cur = ws + OFF_S2 + (size_t)s * 32768;
    float* gs    = ws + OFF_G  + (size_t)s * 16384;
    // cell2(s-1): reads c2 buf[(s-1)&1], writes buf[s&1]
    float* c2old = ws + (((s - 1) & 1) ? OFF_C2B : OFF_C2);
    float* c2new = ws + ((s & 1) ? OFF_C2B : OFF_C2);
    hipLaunchKernelGGL(k_escore2, dim3(256), dim3(256), 0, stream,
                       s, ws + OFF_P2, bss2, s2old, s2cur, c2old, c2new,
                       keys, Wdec, ws + OFF_ENCPROJ, ws + OFF_CWT, ws + OFF_CUM,
                       Wself, ws + OFF_SC);
    hipLaunchKernelGGL(k_attng, dim3(256), dim3(256), 0, stream,
                       ws + OFF_SC, e_out, ws + OFF_CUM, gs,
                       out + OUT_ATTN + (size_t)s * 200);
    hipLaunchKernelGGL(k_b1g, dim3(448), dim3(256), 0, stream,
                       ws + OFF_PRE2 + (size_t)s * 8192, s1old, gs, Wys, Wss, Wgs,
                       ws + OFF_P1);
    hipLaunchKernelGGL(k_cell1, dim3(128), dim3(256), 0, stream,
                       ws + OFF_P1, bgs, s1old, s1new, ws + OFF_C1, keys + s * 8 + 4);
    hipLaunchKernelGGL(k_b2g, dim3(512), dim3(256), 0, stream,
                       s1new, s2cur, Wis, Wss2, ws + OFF_P2);
  }
  // cell2(249): reads c2 buf[249&1]=buf1, writes buf0. s2 slot 250 for k_frame.
  hipLaunchKernelGGL(k_cellfin, dim3(128), dim3(256), 0, stream,
                     ws + OFF_P2, bss2, ws + OFF_S2 + (size_t)249 * 32768,
                     ws + OFF_S2 + (size_t)250 * 32768,
                     ws + OFF_C2B, ws + OFF_C2, keys + 249 * 8 + 6);
  hipLaunchKernelGGL(k_frame, dim3(250), dim3(256), 0, stream,
                     ws + OFF_S2, ws + OFF_G, Wf, bf, Wt, bt, out, out + OUT_TOK);
}

// Round 7
// 15269.469 us; speedup vs baseline: 6.9241x; 1.6028x over previous
//
#include <hip/hip_runtime.h>
#include <cstdint>
#include <cstddef>

// ---------------------------------------------------------------------------
// Tacotron2 decoder, MI355X. Round 11: R10 with the escore indexing bug fixed
// (conv window must use GLOBAL l into ca[] — ca spans the full padded cum row;
// R10 used local lo, corrupting p>0 blocks). Otherwise identical to R10:
//  1. k_escore score loop: wave-parallel (a-half x l-subset per wave), same
//     value-to-lane mapping + butterfly tree + half-sum combine -> bit-exact,
//     26 __syncthreads -> 2.
//  2. CWt stored transposed [k][128] (same values): conv-weight loads coalesced.
// ---------------------------------------------------------------------------

static constexpr int NSTEP = 250;

// workspace offsets (floats). total = 19,322,880 floats (~77.3 MB)
static constexpr size_t OFF_ENCPROJ = 0;               // 819200
static constexpr size_t OFF_CWT     = 819200;          // 4096
static constexpr size_t OFF_KEYS    = 823296;          // 2048 (250*8 uints)
static constexpr size_t OFF_PRE2    = 825344;          // 2048000
static constexpr size_t OFF_G       = 2873344;         // 4096000
static constexpr size_t OFF_S2      = 6969344;         // 251*32768 = 8224768
static constexpr size_t OFF_S1      = 15194112;        // 65536 (ping-pong)
static constexpr size_t OFF_C1      = 15259648;        // 32768
static constexpr size_t OFF_C2      = 15292416;        // 32768
static constexpr size_t OFF_CUM     = 15325184;        // 8192 (6400 used)
static constexpr size_t OFF_DPART   = 15333376;        // 32768 (32*8*128)
static constexpr size_t OFF_SC      = 15366144;        // 8192 (6400 used)
static constexpr size_t OFF_P1      = 15390720;        // 14*32*4096 = 1835008
static constexpr size_t OFF_P2      = 17225728;        // 16*32*4096 = 2097152

// d_out offsets (floats)
static constexpr size_t OUT_TOK  = 1280000;
static constexpr size_t OUT_ATTN = 1296000;

// ---------------------------------------------------------------------------
// Threefry-2x32 (JAX partitionable split — verified bit-exact)
// ---------------------------------------------------------------------------
__device__ __forceinline__ uint2 threefry(unsigned k0, unsigned k1, unsigned c0, unsigned c1) {
  unsigned ks2 = k0 ^ k1 ^ 0x1BD11BDAu;
  unsigned x0 = c0 + k0, x1 = c1 + k1;
#define TFR(rot) { x0 += x1; x1 = (x1 << (rot)) | (x1 >> (32 - (rot))); x1 ^= x0; }
  TFR(13) TFR(15) TFR(26) TFR(6)   x0 += k1;  x1 += ks2 + 1u;
  TFR(17) TFR(29) TFR(16) TFR(24)  x0 += ks2; x1 += k0 + 2u;
  TFR(13) TFR(15) TFR(26) TFR(6)   x0 += k0;  x1 += k1 + 3u;
  TFR(17) TFR(29) TFR(16) TFR(24)  x0 += k1;  x1 += ks2 + 4u;
  TFR(13) TFR(15) TFR(26) TFR(6)   x0 += ks2; x1 += k0 + 5u;
#undef TFR
  return make_uint2(x0, x1);
}

__device__ __forceinline__ float u32_to_uniform(unsigned b) {
  return __uint_as_float((b >> 9) | 0x3f800000u) - 1.0f;
}

__device__ __forceinline__ float rng_uniform(unsigned k0, unsigned k1, unsigned i) {
  uint2 h = threefry(k0, k1, 0u, i);
  return u32_to_uniform(h.x ^ h.y);
}

__device__ __forceinline__ float gatef(float x) { return tanhf(x * 0.5f) * 0.5f + 0.5f; }

#define FMA4(A, S, W) { (A).x = fmaf((S), (W).x, (A).x); (A).y = fmaf((S), (W).y, (A).y); \
                        (A).z = fmaf((S), (W).z, (A).z); (A).w = fmaf((S), (W).w, (A).w); }

// ---------------------------------------------------------------------------
// k_init: zero states + cum + dpart (step-0 decproj == 0 since s2_0 == 0),
// attn rows 250..499, derive per-step RNG keys, precompute CWt (transposed:
// cwtT[k][a], 31x128 used of 32x128 slot; same per-(k,a) FMA order as before).
// ---------------------------------------------------------------------------
__global__ __launch_bounds__(256) void k_init(float* __restrict__ ws, float* __restrict__ out,
                                              const float* __restrict__ conv_w,
                                              const float* __restrict__ Wcp) {
  const size_t NZERO1 = 172032;   // s1(2x)+c1+c2+cum+dpart contiguous at OFF_S1
  const size_t NZERO2 = 32768;    // s2_all slot 0
  const size_t NATTN  = 1600000;  // attn rows 250..499
  const size_t NKEYS  = 250;
  const size_t NCWT   = 4096;
  const size_t TOTAL  = NZERO1 + NZERO2 + NATTN + NKEYS + NCWT;
  unsigned* keys = (unsigned*)(ws + OFF_KEYS);
  for (size_t i = (size_t)blockIdx.x * 256 + threadIdx.x; i < TOTAL; i += (size_t)gridDim.x * 256) {
    if (i < NZERO1) {
      ws[OFF_S1 + i] = 0.f;
    } else if (i < NZERO1 + NZERO2) {
      ws[OFF_S2 + (i - NZERO1)] = 0.f;
    } else if (i < NZERO1 + NZERO2 + NATTN) {
      size_t r = i - NZERO1 - NZERO2;
      size_t b = r / 50000, rem = r % 50000;
      out[OUT_ATTN + b * 100000 + 50000 + rem] = 0.f;
    } else if (i < NZERO1 + NZERO2 + NATTN + NKEYS) {
      int s = (int)(i - NZERO1 - NZERO2 - NATTN);
      uint2 F = threefry(0u, 1234u, 0u, (unsigned)s);
      uint2 kd1 = threefry(F.x, F.y, 0u, 0u);
      uint2 kd2 = threefry(F.x, F.y, 0u, 1u);
      uint2 kz1 = threefry(F.x, F.y, 0u, 2u);
      uint2 kz2 = threefry(F.x, F.y, 0u, 3u);
      keys[s * 8 + 0] = kd1.x; keys[s * 8 + 1] = kd1.y;
      keys[s * 8 + 2] = kd2.x; keys[s * 8 + 3] = kd2.y;
      keys[s * 8 + 4] = kz1.x; keys[s * 8 + 5] = kz1.y;
      keys[s * 8 + 6] = kz2.x; keys[s * 8 + 7] = kz2.y;
    } else {
      size_t r = i - NZERO1 - NZERO2 - NATTN - NKEYS;   // [0,4096)
      int kk = (int)(r >> 7), a = (int)(r & 127);       // transposed layout
      float v = 0.f;
      if (kk < 31) {
        for (int f = 0; f < 32; ++f) v = fmaf(conv_w[f * 31 + kk], Wcp[f * 128 + a], v);
      }
      ws[OFF_CWT + r] = v;   // cwtT[k][a], row stride 128
    }
  }
}

// ---------------------------------------------------------------------------
// k_encproj: encproj = e_outputs @ W_encproj + b  ([6400,512]@[512,128])
// ---------------------------------------------------------------------------
__global__ __launch_bounds__(256) void k_encproj(const float* __restrict__ e_out,
                                                 const float* __restrict__ Wenc,
                                                 const float* __restrict__ benc,
                                                 float* __restrict__ encproj) {
  __shared__ __align__(16) float xs[32 * 516];
  int t = threadIdx.x;
  int r0 = blockIdx.x * 32;
  for (int i = 0; i < 64; ++i) {
    int idx = t + 256 * i; int rb = idx >> 9, kk = idx & 511;
    xs[rb * 516 + kk] = e_out[(size_t)(r0 + rb) * 512 + kk];
  }
  __syncthreads();
  int a = t & 127, rh = t >> 7;
  float acc[16];
#pragma unroll
  for (int r = 0; r < 16; ++r) acc[r] = 0.f;
  const float4* xv = (const float4*)xs;
  for (int k4 = 0; k4 < 128; ++k4) {
    const float* wp = Wenc + (size_t)(k4 * 4) * 128 + a;
    float w0 = wp[0], w1 = wp[128], w2 = wp[256], w3 = wp[384];
#pragma unroll
    for (int r = 0; r < 16; ++r) {
      float4 x4 = xv[(rh * 16 + r) * 129 + k4];
      acc[r] = fmaf(x4.x, w0, acc[r]); acc[r] = fmaf(x4.y, w1, acc[r]);
      acc[r] = fmaf(x4.z, w2, acc[r]); acc[r] = fmaf(x4.w, w3, acc[r]);
    }
  }
  float bb = benc[a];
  for (int r = 0; r < 16; ++r)
    encproj[(size_t)(r0 + rh * 16 + r) * 128 + a] = acc[r] + bb;
}

// ---------------------------------------------------------------------------
// k_prenet: all 250 steps, exact dropout
// ---------------------------------------------------------------------------
__global__ __launch_bounds__(256) void k_prenet(const float* __restrict__ mel,
                                                const float* __restrict__ W1, const float* __restrict__ b1,
                                                const float* __restrict__ W2, const float* __restrict__ b2,
                                                const unsigned* __restrict__ keys,
                                                float* __restrict__ pre2_all) {
  int s = blockIdx.x, t = threadIdx.x;
  __shared__ __align__(16) float prev[32 * 80];
  __shared__ __align__(16) float p1[32 * 256];
  for (int i = 0; i < 10; ++i) {
    int idx = t + 256 * i;
    int bb = idx / 80, vv = idx % 80;
    prev[idx] = (s == 0) ? 0.f : mel[(size_t)bb * 40000 + (size_t)(2 * s - 1) * 80 + vv];
  }
  __syncthreads();
  unsigned kd10 = keys[s * 8 + 0], kd11 = keys[s * 8 + 1];
  unsigned kd20 = keys[s * 8 + 2], kd21 = keys[s * 8 + 3];
  float acc[32];
  float bias = b1[t];
#pragma unroll
  for (int b = 0; b < 32; ++b) acc[b] = bias;
  for (int k4 = 0; k4 < 20; ++k4) {
    const float* wp = W1 + (size_t)(k4 * 4) * 256 + t;
    float w0 = wp[0], w1 = wp[256], w2 = wp[512], w3 = wp[768];
#pragma unroll
    for (int b = 0; b < 32; ++b) {
      float4 x4 = *(const float4*)(prev + b * 80 + k4 * 4);
      acc[b] = fmaf(x4.x, w0, acc[b]); acc[b] = fmaf(x4.y, w1, acc[b]);
      acc[b] = fmaf(x4.z, w2, acc[b]); acc[b] = fmaf(x4.w, w3, acc[b]);
    }
  }
#pragma unroll
  for (int b = 0; b < 32; ++b) {
    float r = fmaxf(acc[b], 0.f);
    float u = rng_uniform(kd10, kd11, (unsigned)(b * 256 + t));
    p1[b * 256 + t] = (u < 0.5f) ? r * 2.f : 0.f;
  }
  __syncthreads();
  float bias2 = b2[t];
#pragma unroll
  for (int b = 0; b < 32; ++b) acc[b] = bias2;
  for (int k4 = 0; k4 < 64; ++k4) {
    const float* wp = W2 + (size_t)(k4 * 4) * 256 + t;
    float w0 = wp[0], w1 = wp[256], w2 = wp[512], w3 = wp[768];
#pragma unroll
    for (int b = 0; b < 32; ++b) {
      float4 x4 = *(const float4*)(p1 + b * 256 + k4 * 4);
      acc[b] = fmaf(x4.x, w0, acc[b]); acc[b] = fmaf(x4.y, w1, acc[b]);
      acc[b] = fmaf(x4.z, w2, acc[b]); acc[b] = fmaf(x4.w, w3, acc[b]);
    }
  }
  for (int b = 0; b < 32; ++b) {
    float r = fmaxf(acc[b], 0.f);
    float u = rng_uniform(kd20, kd21, (unsigned)(b * 256 + t));
    pre2_all[(size_t)(s * 32 + b) * 256 + t] = (u < 0.5f) ? r * 2.f : 0.f;
  }
}

// ---------------------------------------------------------------------------
// k_escore: conv + tanh + score. grid 256 = (b, lchunk p of 25 l's).
// Wave-parallel score loop. Wave w = (lseg = w>>1, half = w&1): lane la holds
// a = half*64+la — identical value-to-lane mapping and butterfly tree as R5
// (half-sum combine preserved) -> bit-exact, 2 syncs total. ca indexed by
// GLOBAL l (R10 bug was local lo).
// ---------------------------------------------------------------------------
__global__ __launch_bounds__(256) void k_escore(const float* __restrict__ dpart,
                                                const float* __restrict__ encproj,
                                                const float* __restrict__ cwt,
                                                const float* __restrict__ cum,
                                                const float* __restrict__ Wself,
                                                float* __restrict__ sglob) {
  int b = blockIdx.x & 31, p = blockIdx.x >> 5;
  int t = threadIdx.x;
  __shared__ float dp[128];
  __shared__ float ca[232];
  __shared__ float hs[2][32];
  if (t < 128) {
    float acc = 0.f;
#pragma unroll
    for (int q = 0; q < 8; ++q) acc += dpart[(b * 8 + q) * 128 + t];
    dp[t] = acc;
  }
  if (t < 232) ca[t] = (t >= 15 && t < 215) ? cum[b * 200 + (t - 15)] : 0.f;
  __syncthreads();
  {
    int w = t >> 6, la = t & 63;
    int half = w & 1, lseg = w >> 1;          // lseg 0: l 0..12, lseg 1: l 13..24
    int a = half * 64 + la;
    float cwr[31];
#pragma unroll
    for (int k = 0; k < 31; ++k) cwr[k] = cwt[k * 128 + a];   // transposed, coalesced
    float wself = Wself[a];
    float dpr = dp[a];
    int l0 = lseg * 13, lN = lseg ? 12 : 13;
    for (int i = 0; i < lN; ++i) {
      int lo = l0 + i;
      int l = p * 25 + lo;
      float conv = 0.f;
#pragma unroll
      for (int k = 0; k < 31; ++k) conv = fmaf(ca[l + k], cwr[k], conv);
      float e = tanhf(dpr + encproj[(size_t)(b * 200 + l) * 128 + a] + conv);
      float v = e * wself;
#pragma unroll
      for (int off = 32; off > 0; off >>= 1) v += __shfl_xor(v, off, 64);
      if (la == 0) hs[half][lo] = v;
    }
  }
  __syncthreads();
  if (t < 25) sglob[b * 200 + p * 25 + t] = hs[0][t] + hs[1][t];
}

// ---------------------------------------------------------------------------
// k_attng: softmax (redundant/block) + g slices. grid 256 = (b, dchunk p of 64).
// p==0 block also writes alpha to attn_out and updates cum.
// ---------------------------------------------------------------------------
__global__ __launch_bounds__(256) void k_attng(const float* __restrict__ sglob,
                                               const float* __restrict__ e_out,
                                               float* __restrict__ cum,
                                               float* __restrict__ g_out,
                                               float* __restrict__ attn_out) {
  int b = blockIdx.x & 31, p = blockIdx.x >> 5;
  int t = threadIdx.x;
  __shared__ float sc[200];
  __shared__ float red[8];
  __shared__ float bcv[2];
  __shared__ float gpart[4][64];
  if (t < 200) sc[t] = sglob[b * 200 + t];
  __syncthreads();
  float v = (t < 200) ? sc[t] : -3.4e38f;
#pragma unroll
  for (int off = 32; off > 0; off >>= 1) v = fmaxf(v, __shfl_xor(v, off, 64));
  if ((t & 63) == 0) red[t >> 6] = v;
  __syncthreads();
  if (t == 0) bcv[0] = fmaxf(fmaxf(red[0], red[1]), fmaxf(red[2], red[3]));
  __syncthreads();
  float mx = bcv[0];
  float ex = (t < 200) ? expf(sc[t] - mx) : 0.f;
  float sv = ex;
#pragma unroll
  for (int off = 32; off > 0; off >>= 1) sv += __shfl_xor(sv, off, 64);
  if ((t & 63) == 0) red[4 + (t >> 6)] = sv;
  __syncthreads();
  if (t == 0) bcv[1] = (red[4] + red[5]) + (red[6] + red[7]);
  __syncthreads();
  float denom = bcv[1];
  if (t < 200) {
    float al = ex / denom;
    sc[t] = al;
    if (p == 0) {
      cum[b * 200 + t] += al;
      attn_out[(size_t)b * 100000 + t] = al;
    }
  }
  __syncthreads();
  int d = p * 64 + (t & 63), lq = t >> 6;
  const float* eb = e_out + (size_t)b * 102400 + d;
  float acc = 0.f;
  for (int l = lq * 50; l < lq * 50 + 50; ++l) acc = fmaf(sc[l], eb[(size_t)l * 512], acc);
  gpart[lq][t & 63] = acc;
  __syncthreads();
  if (t < 64)
    g_out[b * 512 + p * 64 + t] = (gpart[0][t] + gpart[1][t]) + (gpart[2][t] + gpart[3][t]);
}

// ---------------------------------------------------------------------------
// LSTM GEMM partials only. Block = (coltile jt: gate-quad cols, K-chunk c).
// No atomics, no fences — the kernel boundary publishes the partials.
// ---------------------------------------------------------------------------
__device__ __forceinline__ void gemm_body(
    const float* __restrict__ W0, int k0,
    float* __restrict__ part, int c, int jt,
    const float* __restrict__ xs /*staged 32x132*/) {
  int t = threadIdx.x;
  int jq = t & 31, bq = t >> 5;
  int j = jt * 32 + jq;
  float4 acc[4];
  acc[0] = acc[1] = acc[2] = acc[3] = make_float4(0, 0, 0, 0);
  const float4* xv = (const float4*)xs;
  const float* Wb = W0 + (size_t)k0 * 4096 + j;
#pragma unroll 4
  for (int k4 = 0; k4 < 32; ++k4) {
    float4 xq[4];
    xq[0] = xv[(bq * 4 + 0) * 33 + k4];
    xq[1] = xv[(bq * 4 + 1) * 33 + k4];
    xq[2] = xv[(bq * 4 + 2) * 33 + k4];
    xq[3] = xv[(bq * 4 + 3) * 33 + k4];
    const float* wr = Wb + (size_t)(k4 * 4) * 4096;
#pragma unroll
    for (int ks = 0; ks < 4; ++ks) {
      float wi = wr[0], wf = wr[1024], wc = wr[2048], wo = wr[3072];
      wr += 4096;
#pragma unroll
      for (int r = 0; r < 4; ++r) {
        float xval = ((const float*)&xq[r])[ks];
        acc[r].x = fmaf(xval, wi, acc[r].x);
        acc[r].y = fmaf(xval, wf, acc[r].y);
        acc[r].z = fmaf(xval, wc, acc[r].z);
        acc[r].w = fmaf(xval, wo, acc[r].w);
      }
    }
  }
  float* pb = part + (size_t)c * 131072 + (size_t)(bq * 4) * 4096 + j;
#pragma unroll
  for (int r = 0; r < 4; ++r) {
    float* pr = pb + r * 4096;
    pr[0] = acc[r].x; pr[1024] = acc[r].y; pr[2048] = acc[r].z; pr[3072] = acc[r].w;
  }
}

// LSTM1 GEMM: x = [pre2(256) | s1old(1024) | g(512)], 14 chunks. grid 448.
__global__ __launch_bounds__(256) void k_b1g(
    const float* __restrict__ pre2_s, const float* __restrict__ s1old,
    const float* __restrict__ g_s,
    const float* __restrict__ Wys, const float* __restrict__ Wss, const float* __restrict__ Wgs,
    float* __restrict__ part) {
  int t = threadIdx.x;
  int jt = blockIdx.x & 31, c = blockIdx.x >> 5;   // c in 0..13
  __shared__ __align__(16) float xs[32 * 132];
  {
    int r = t >> 3, kq = t & 7;
    const float* src;
    if (c < 2)       src = pre2_s + r * 256 + c * 128;
    else if (c < 10) src = s1old + r * 1024 + (c - 2) * 128;
    else             src = g_s + r * 512 + (c - 10) * 128;
    const float4* s4 = (const float4*)(src + kq * 16);
    float4* d4 = (float4*)(xs + r * 132 + kq * 16);
    d4[0] = s4[0]; d4[1] = s4[1]; d4[2] = s4[2]; d4[3] = s4[3];
  }
  const float* W0; int k0;
  if (c < 2)       { W0 = Wys; k0 = c * 128; }
  else if (c < 10) { W0 = Wss; k0 = (c - 2) * 128; }
  else             { W0 = Wgs; k0 = (c - 10) * 128; }
  __syncthreads();
  gemm_body(W0, k0, part, c, jt, xs);
}

// LSTM2 GEMM: x = [s1new(1024) | s2prev(1024)], 16 chunks. grid 512.
__global__ __launch_bounds__(256) void k_b2g(
    const float* __restrict__ s1new, const float* __restrict__ s2prev,
    const float* __restrict__ Wis, const float* __restrict__ Wss2,
    float* __restrict__ part) {
  int t = threadIdx.x;
  int jt = blockIdx.x & 31, c = blockIdx.x >> 5;   // c in 0..15
  __shared__ __align__(16) float xs[32 * 132];
  {
    int r = t >> 3, kq = t & 7;
    const float* src = (c < 8) ? (s1new + r * 1024 + c * 128)
                               : (s2prev + r * 1024 + (c - 8) * 128);
    const float4* s4 = (const float4*)(src + kq * 16);
    float4* d4 = (float4*)(xs + r * 132 + kq * 16);
    d4[0] = s4[0]; d4[1] = s4[1]; d4[2] = s4[2]; d4[3] = s4[3];
  }
  const float* W0; int k0;
  if (c < 8) { W0 = Wis;  k0 = c * 128; }
  else       { W0 = Wss2; k0 = (c - 8) * 128; }
  __syncthreads();
  gemm_body(W0, k0, part, c, jt, xs);
}

// ---------------------------------------------------------------------------
// k_cell1: reduce 14 partial chunks + bias + gates + zoneout for LSTM1.
// grid 128 x 256 = one thread per (b,j) element.
// ---------------------------------------------------------------------------
__global__ __launch_bounds__(256) void k_cell1(
    const float* __restrict__ part, const float* __restrict__ bias,
    const float* __restrict__ sold, float* __restrict__ snew, float* __restrict__ cst,
    const unsigned* __restrict__ keyp) {
  int e = blockIdx.x * 256 + threadIdx.x;   // [0, 32768)
  int b = e >> 10, j = e & 1023;
  float gi = bias[j], gf = bias[1024 + j], gc = bias[2048 + j], go = bias[3072 + j];
  const float* pc = part + (size_t)b * 4096 + j;
#pragma unroll
  for (int cc = 0; cc < 14; ++cc) {
    const float* p2 = pc + (size_t)cc * 131072;
    gi += p2[0]; gf += p2[1024]; gc += p2[2048]; go += p2[3072];
  }
  float u = rng_uniform(keyp[0], keyp[1], (unsigned)e);
  float m = floorf(u + 0.1f);
  float co = cst[e], so = sold[e];
  float cn = fmaf(gatef(gf), co, gatef(gi) * tanhf(gc));
  float cnew = (m > 0.5f) ? co : cn;
  float sn = (m > 0.5f) ? so : (gatef(go) * tanhf(cnew));
  cst[e] = cnew;
  snew[e] = sn;
}

// ---------------------------------------------------------------------------
// k_cell2dp: LSTM2 cell (16 chunks) fused with next step's decproj partials.
// grid 256 = (b 0..31, p 0..7).
// ---------------------------------------------------------------------------
__global__ __launch_bounds__(256) void k_cell2dp(
    const float* __restrict__ part, const float* __restrict__ bias,
    const float* __restrict__ sold, float* __restrict__ snew, float* __restrict__ cst,
    const unsigned* __restrict__ keyp,
    const float* __restrict__ Wdec, float* __restrict__ dpart) {
  int b = blockIdx.x & 31, p = blockIdx.x >> 5;
  int t = threadIdx.x;
  __shared__ float s2l[128];
  __shared__ float dtmp[256];
  if (t < 128) {
    int j = p * 128 + t;
    int e = b * 1024 + j;
    float gi = bias[j], gf = bias[1024 + j], gc = bias[2048 + j], go = bias[3072 + j];
    const float* pc = part + (size_t)b * 4096 + j;
#pragma unroll
    for (int cc = 0; cc < 16; ++cc) {
      const float* p2 = pc + (size_t)cc * 131072;
      gi += p2[0]; gf += p2[1024]; gc += p2[2048]; go += p2[3072];
    }
    float u = rng_uniform(keyp[0], keyp[1], (unsigned)e);
    float m = floorf(u + 0.1f);
    float co = cst[e], so = sold[e];
    float cn = fmaf(gatef(gf), co, gatef(gi) * tanhf(gc));
    float cnew = (m > 0.5f) ? co : cn;
    float sn = (m > 0.5f) ? so : (gatef(go) * tanhf(cnew));
    cst[e] = cnew;
    snew[e] = sn;
    s2l[t] = sn;
  }
  __syncthreads();
  int a = t & 127, h = t >> 7;
  const float* wp = Wdec + (size_t)(p * 128 + h * 64) * 128 + a;
  float acc = 0.f;
#pragma unroll 8
  for (int r = 0; r < 64; ++r) acc = fmaf(s2l[h * 64 + r], wp[(size_t)r * 128], acc);
  dtmp[t] = acc;
  __syncthreads();
  if (t < 128) dpart[(b * 8 + p) * 128 + t] = dtmp[t] + dtmp[t + 128];
}

// ---------------------------------------------------------------------------
// k_frame: deferred frame/token projection. grid 250.
// ---------------------------------------------------------------------------
__global__ __launch_bounds__(256) void k_frame(const float* __restrict__ s2_all,
                                               const float* __restrict__ g_all,
                                               const float* __restrict__ Wf,
                                               const float* __restrict__ bf,
                                               const float* __restrict__ Wt,
                                               const float* __restrict__ bt,
                                               float* __restrict__ out_frame,
                                               float* __restrict__ out_tok) {
  int s = blockIdx.x, t = threadIdx.x;
  __shared__ __align__(16) float xs[32 * 516];
  int b = t >> 3, ci = t & 7;
  int tb = t >> 1, tr = t & 1;
  float4 acc[5];
#pragma unroll
  for (int r = 0; r < 5; ++r) acc[r] = make_float4(0, 0, 0, 0);
  float tok = 0.f;
  for (int ch = 0; ch < 3; ++ch) {
    for (int i = 0; i < 64; ++i) {
      int idx = t + 256 * i;
      int rb = idx >> 9, kk = idx & 511;
      float vsrc = (ch < 2) ? s2_all[(size_t)(s + 1) * 32768 + rb * 1024 + ch * 512 + kk]
                            : g_all[(size_t)s * 16384 + rb * 512 + kk];
      xs[rb * 516 + kk] = vsrc;
    }
    __syncthreads();
    const float4* xv = (const float4*)xs;
    for (int k4 = 0; k4 < 128; ++k4) {
      float4 x4 = xv[b * 129 + k4];
      int kglob = ch * 512 + k4 * 4;
#pragma unroll
      for (int rep = 0; rep < 5; ++rep) {
        int c4 = ci * 4 + rep * 32;
        const float* wrow = Wf + (size_t)kglob * 160 + c4;
        float4 w0 = *(const float4*)(wrow);
        float4 w1 = *(const float4*)(wrow + 160);
        float4 w2 = *(const float4*)(wrow + 320);
        float4 w3 = *(const float4*)(wrow + 480);
        FMA4(acc[rep], x4.x, w0); FMA4(acc[rep], x4.y, w1);
        FMA4(acc[rep], x4.z, w2); FMA4(acc[rep], x4.w, w3);
      }
      if (t < 64) {
        float4 xt = xv[tb * 129 + k4];
        tok = fmaf(xt.x, Wt[(size_t)(kglob + 0) * 2 + tr], tok);
        tok = fmaf(xt.y, Wt[(size_t)(kglob + 1) * 2 + tr], tok);
        tok = fmaf(xt.z, Wt[(size_t)(kglob + 2) * 2 + tr], tok);
        tok = fmaf(xt.w, Wt[(size_t)(kglob + 3) * 2 + tr], tok);
      }
    }
    __syncthreads();
  }
#pragma unroll
  for (int rep = 0; rep < 5; ++rep) {
    float vals[4] = {acc[rep].x, acc[rep].y, acc[rep].z, acc[rep].w};
#pragma unroll
    for (int jj = 0; jj < 4; ++jj) {
      int cc = ci * 4 + rep * 32 + jj;
      float val = vals[jj] + bf[cc];
      int row = 2 * s + (cc >= 80 ? 1 : 0);
      int col = cc - (cc >= 80 ? 80 : 0);
      out_frame[(size_t)b * 40000 + (size_t)row * 80 + col] = val;
    }
  }
  if (t < 64) out_tok[(size_t)tb * 500 + 2 * s + tr] = tok + bt[tr];
}

// ---------------------------------------------------------------------------
extern "C" void kernel_launch(void* const* d_in, const int* in_sizes, int n_in,
                              void* d_out_v, int out_size, void* d_ws, size_t ws_size,
                              hipStream_t stream) {
  (void)in_sizes; (void)n_in; (void)out_size; (void)ws_size;
  const float* mel      = (const float*)d_in[0];
  const float* e_out    = (const float*)d_in[1];
  const float* conv_w   = (const float*)d_in[2];
  const float* Wcp      = (const float*)d_in[3];
  const float* Wenc     = (const float*)d_in[4];
  const float* benc     = (const float*)d_in[5];
  const float* Wdec     = (const float*)d_in[6];
  const float* Wself    = (const float*)d_in[7];
  const float* Wp1      = (const float*)d_in[8];
  const float* bp1      = (const float*)d_in[9];
  const float* Wp2      = (const float*)d_in[10];
  const float* bp2      = (const float*)d_in[11];
  const float* Wys      = (const float*)d_in[12];
  const float* Wss      = (const float*)d_in[13];
  const float* Wgs      = (const float*)d_in[14];
  const float* bgs      = (const float*)d_in[15];
  const float* Wis      = (const float*)d_in[16];
  const float* Wss2     = (const float*)d_in[17];
  const float* bss2     = (const float*)d_in[18];
  const float* Wf       = (const float*)d_in[19];
  const float* bf       = (const float*)d_in[20];
  const float* Wt       = (const float*)d_in[21];
  const float* bt       = (const float*)d_in[22];
  float* ws  = (float*)d_ws;
  float* out = (float*)d_out_v;
  const unsigned* keys = (const unsigned*)(ws + OFF_KEYS);

  hipLaunchKernelGGL(k_init, dim3(1024), dim3(256), 0, stream, ws, out, conv_w, Wcp);
  hipLaunchKernelGGL(k_encproj, dim3(200), dim3(256), 0, stream, e_out, Wenc, benc, ws + OFF_ENCPROJ);
  hipLaunchKernelGGL(k_prenet, dim3(250), dim3(256), 0, stream, mel, Wp1, bp1, Wp2, bp2, keys, ws + OFF_PRE2);

  for (int s = 0; s < NSTEP; ++s) {
    float* s1old = ws + OFF_S1 + (size_t)(s & 1) * 32768;
    float* s1new = ws + OFF_S1 + (size_t)((s + 1) & 1) * 32768;
    float* s2s   = ws + OFF_S2 + (size_t)s * 32768;
    float* s2n   = ws + OFF_S2 + (size_t)(s + 1) * 32768;
    float* gs    = ws + OFF_G  + (size_t)s * 16384;
    hipLaunchKernelGGL(k_escore, dim3(256), dim3(256), 0, stream,
                       ws + OFF_DPART, ws + OFF_ENCPROJ, ws + OFF_CWT, ws + OFF_CUM,
                       Wself, ws + OFF_SC);
    hipLaunchKernelGGL(k_attng, dim3(256), dim3(256), 0, stream,
                       ws + OFF_SC, e_out, ws + OFF_CUM, gs,
                       out + OUT_ATTN + (size_t)s * 200);
    hipLaunchKernelGGL(k_b1g, dim3(448), dim3(256), 0, stream,
                       ws + OFF_PRE2 + (size_t)s * 8192, s1old, gs, Wys, Wss, Wgs,
                       ws + OFF_P1);
    hipLaunchKernelGGL(k_cell1, dim3(128), dim3(256), 0, stream,
                       ws + OFF_P1, bgs, s1old, s1new, ws + OFF_C1, keys + s * 8 + 4);
    hipLaunchKernelGGL(k_b2g, dim3(512), dim3(256), 0, stream,
                       s1new, s2s, Wis, Wss2, ws + OFF_P2);
    hipLaunchKernelGGL(k_cell2dp, dim3(256), dim3(256), 0, stream,
                       ws + OFF_P2, bss2, s2s, s2n, ws + OFF_C2, keys + s * 8 + 6,
                       Wdec, ws + OFF_DPART);
  }
  hipLaunchKernelGGL(k_frame, dim3(250), dim3(256), 0, stream,
                     ws + OFF_S2, ws + OFF_G, Wf, bf, Wt, bt, out, out + OUT_TOK);
}